// Round 2
// baseline (1057.589 us; speedup 1.0000x reference)
//
#include <hip/hip_runtime.h>
#include <hip/hip_bf16.h>
#include <math.h>

// Problem dims
#define NV 32000
#define NC 4096
#define NS 32
#define NH 512
#define NB 32
#define NT 256

typedef short s16x8 __attribute__((ext_vector_type(8)));
typedef float f32x4 __attribute__((ext_vector_type(4)));

// ---------------- helpers ----------------
__device__ __forceinline__ float wredMax(float v){
  #pragma unroll
  for (int o = 32; o; o >>= 1) v = fmaxf(v, __shfl_xor(v, o, 64));
  return v;
}
__device__ __forceinline__ float wredSum(float v){
  #pragma unroll
  for (int o = 32; o; o >>= 1) v += __shfl_xor(v, o, 64);
  return v;
}
// order-preserving float<->int for atomicMax (no NaN/Inf in inputs)
__device__ __forceinline__ int f2ord(float f){ int i = __float_as_int(f); return i >= 0 ? i : (i ^ 0x7fffffff); }
__device__ __forceinline__ float ord2f(int i){ return __int_as_float(i >= 0 ? i : (i ^ 0x7fffffff)); }

// f32 -> bf16 round-nearest-even (bit trick; inputs are well-behaved, no NaN/Inf)
__device__ __forceinline__ unsigned short f2bf(float x){
  unsigned int u = __float_as_uint(x);
  return (unsigned short)((u + 0x7fffu + ((u >> 16) & 1u)) >> 16);
}
__device__ __forceinline__ float bf2f(unsigned short h){
  return __uint_as_float((unsigned int)h << 16);
}

// ---------------- split conversion: f32 [R][512] -> bf16 [R][1024] = [hi(512) | lo(512)] ----------------
__device__ __forceinline__ void conv_body(const float* __restrict__ src,
                                          unsigned short* __restrict__ dst, int idx)
{
  const float* s = src + (size_t)idx * 8;
  float4 f0 = *(const float4*)s;
  float4 f1 = *(const float4*)(s + 4);
  float fv[8] = {f0.x, f0.y, f0.z, f0.w, f1.x, f1.y, f1.z, f1.w};
  s16x8 vh, vl;
  #pragma unroll
  for (int e = 0; e < 8; ++e) {
    unsigned short h = f2bf(fv[e]);
    vh[e] = (short)h;
    vl[e] = (short)f2bf(fv[e] - bf2f(h));
  }
  int r = idx >> 6, c8 = idx & 63;           // 64 8-elem groups per row (K=512)
  unsigned short* d = dst + (size_t)r * 1024 + c8 * 8;
  *(s16x8*)d = vh;
  *(s16x8*)(d + 512) = vl;
}

struct ConvArgs {
  const float* src[10];
  unsigned short* dst[10];
  int rows[10];
};

__global__ __launch_bounds__(256)
void conv_batch(ConvArgs a)
{
  int z = blockIdx.y;
  int idx = blockIdx.x * 256 + threadIdx.x;
  if (idx >= a.rows[z] * 64) return;
  conv_body(a.src[z], a.dst[z], idx);
}

__global__ __launch_bounds__(256)
void conv_single(const float* __restrict__ src, unsigned short* __restrict__ dst)
{
  int idx = blockIdx.x * 256 + threadIdx.x;   // grid sized exactly: 4096*64/256 blocks
  conv_body(src, dst, idx);
}

// ---------------- split-bf16 MFMA NT GEMM ----------------
// Logical op: C[m,n] = act( sum_k A[m,k]*B[n,k] (+bias[n]) (+res[m,n]) ), f32-accurate via
// 3 bf16 products: Ahi*Bhi + Alo*Bhi + Ahi*Blo. A,B given split as [hi(K)|lo(K)], row stride 2K.
// Tile BM x 128, BK=64, 256 threads = 4 waves (2x2), MFMA 16x16x32 bf16.
// LDS XOR-swizzle (T2): byte ^= (row&7)<<4 on both ds_write and ds_read -> conflict-free.
template<int BM, bool RELU, bool BIAS, bool RES>
__global__ __launch_bounds__(256)
void gemm_bf16s(const unsigned short* __restrict__ Asp, const unsigned short* __restrict__ Bsp,
                const float* __restrict__ bias, const float* __restrict__ res,
                float* __restrict__ Co, int M, int N, int K)
{
  constexpr int BN = 128;
  constexpr int MF = BM / 32;     // A frags per wave
  constexpr int NFR = 4;          // B frags per wave
  __shared__ char smem[BM * 128 + BN * 128];   // BM x 64 bf16 + 128 x 64 bf16
  char* smA = smem;
  char* smB = smem + BM * 128;

  const int tid  = threadIdx.x;
  const int lane = tid & 63, w = tid >> 6;
  const int wr = w >> 1, wc = w & 1;
  const int bm = blockIdx.y * BM, bn = blockIdx.x * BN;
  const int lda = 2 * K;
  const int l8 = lane >> 3, s8 = lane & 7;
  const int frow = lane & 15, kgrp = lane >> 4;

  f32x4 acc[MF][NFR] = {};

  #pragma unroll 1
  for (int seg = 0; seg < 3; ++seg) {
    const int aoff = (seg == 1) ? K : 0;
    const int boff = (seg == 2) ? K : 0;
    #pragma unroll 1
    for (int k0 = 0; k0 < K; k0 += 64) {
      // ---- stage A tile (BM x 64) ----
      #pragma unroll
      for (int c = 0; c < MF; ++c) {
        int q = w * MF + c;
        int row = q * 8 + l8;
        s16x8 v = *(const s16x8*)(Asp + (size_t)(bm + row) * lda + aoff + k0 + s8 * 8);
        unsigned int o = (unsigned int)(row * 128 + (s8 << 4));
        o ^= (unsigned int)((row & 7) << 4);
        *(s16x8*)(smA + o) = v;
      }
      // ---- stage B tile (128 x 64) ----
      #pragma unroll
      for (int c = 0; c < NFR; ++c) {
        int q = w * NFR + c;
        int row = q * 8 + l8;
        s16x8 v = *(const s16x8*)(Bsp + (size_t)(bn + row) * lda + boff + k0 + s8 * 8);
        unsigned int o = (unsigned int)(row * 128 + (s8 << 4));
        o ^= (unsigned int)((row & 7) << 4);
        *(s16x8*)(smB + o) = v;
      }
      __syncthreads();
      // ---- compute: 2 MFMA K-steps of 32 ----
      #pragma unroll
      for (int kk = 0; kk < 64; kk += 32) {
        s16x8 af[MF], bfr[NFR];
        #pragma unroll
        for (int im = 0; im < MF; ++im) {
          int ar = wr * (BM / 2) + im * 16 + frow;
          unsigned int o = ((unsigned int)(ar * 128 + (kk + kgrp * 8) * 2)) ^ ((unsigned int)((ar & 7) << 4));
          af[im] = *(const s16x8*)(smA + o);
        }
        #pragma unroll
        for (int jn = 0; jn < NFR; ++jn) {
          int bc = wc * 64 + jn * 16 + frow;
          unsigned int o = ((unsigned int)(bc * 128 + (kk + kgrp * 8) * 2)) ^ ((unsigned int)((bc & 7) << 4));
          bfr[jn] = *(const s16x8*)(smB + o);
        }
        #pragma unroll
        for (int im = 0; im < MF; ++im)
          #pragma unroll
          for (int jn = 0; jn < NFR; ++jn)
            asm volatile("v_mfma_f32_16x16x32_bf16 %0, %1, %2, %0"
                         : "+v"(acc[im][jn]) : "v"(af[im]), "v"(bfr[jn]));
      }
      __syncthreads();
    }
  }
  asm volatile("s_nop 7\n\ts_nop 7" ::: );   // MFMA -> VALU hazard guard before epilogue
  // ---- epilogue: C/D frag mapping col=lane&15, row=(lane>>4)*4+j ----
  #pragma unroll
  for (int im = 0; im < MF; ++im) {
    int row0 = bm + wr * (BM / 2) + im * 16 + kgrp * 4;
    #pragma unroll
    for (int jn = 0; jn < NFR; ++jn) {
      int col = bn + wc * 64 + jn * 16 + frow;
      #pragma unroll
      for (int j = 0; j < 4; ++j) {
        int r = row0 + j;
        float v = acc[im][jn][j];
        if constexpr (BIAS) v += bias[col];
        if constexpr (RES)  v += res[(size_t)r * N + col];
        if constexpr (RELU) v = fmaxf(v, 0.f);
        Co[(size_t)r * N + col] = v;
      }
    }
  }
}

// ---------------- start head: sv[c] = dot(hS[c,:], w3[0,:]) + b3[0] ----------------
__global__ __launch_bounds__(64)
void dot_head(const float* __restrict__ hS, const float* __restrict__ w3,
              const float* __restrict__ b3, float* __restrict__ sv)
{
  int c = blockIdx.x, lane = threadIdx.x;
  const float* hrow = hS + (size_t)c * NH;
  float acc = 0.f;
  #pragma unroll
  for (int e = 0; e < 8; ++e) acc += hrow[lane + e*64] * w3[lane + e*64];
  acc = wredSum(acc);
  if (lane == 0) sv[c] = acc + b3[0];
}

// ---------------- logsumexp over a length-n vector (single block) ----------------
__global__ __launch_bounds__(1024)
void lse_vec(const float* __restrict__ x, int n, float* __restrict__ out)
{
  int tid = threadIdx.x;
  __shared__ float sm[16], ss[16];
  float m = -INFINITY;
  for (int i = tid; i < n; i += 1024) m = fmaxf(m, x[i]);
  m = wredMax(m);
  if ((tid & 63) == 0) sm[tid >> 6] = m;
  __syncthreads();
  m = sm[0];
  #pragma unroll
  for (int wv = 1; wv < 16; ++wv) m = fmaxf(m, sm[wv]);
  float s = 0.f;
  for (int i = tid; i < n; i += 1024) s += expf(x[i] - m);
  s = wredSum(s);
  if ((tid & 63) == 0) ss[tid >> 6] = s;
  __syncthreads();
  if (tid == 0) {
    float tot = 0.f;
    #pragma unroll
    for (int wv = 0; wv < 16; ++wv) tot += ss[wv];
    out[0] = m + logf(tot);
  }
}

// ---------------- per-row LSE of tl over cols 0..NC-2 (col NC-1 forced -inf in ref) ----------------
__global__ __launch_bounds__(256)
void row_lse_trans(const float* __restrict__ tl, float* __restrict__ lse_t)
{
  int c = blockIdx.x;
  const float* row = tl + (size_t)c * NC;
  int tid = threadIdx.x;
  __shared__ float sm[4], ss[4];
  float m = -INFINITY;
  for (int n = tid; n < NC - 1; n += 256) m = fmaxf(m, row[n]);
  m = wredMax(m);
  if ((tid & 63) == 0) sm[tid >> 6] = m;
  __syncthreads();
  m = fmaxf(fmaxf(sm[0], sm[1]), fmaxf(sm[2], sm[3]));
  float s = 0.f;
  for (int n = tid; n < NC - 1; n += 256) s += expf(row[n] - m);
  s = wredSum(s);
  if ((tid & 63) == 0) ss[tid >> 6] = s;
  __syncthreads();
  if (tid == 0) lse_t[c] = m + logf(ss[0] + ss[1] + ss[2] + ss[3]);
}

// ---------------- emission gathered logits: el_g[v,s] = dot(hP[w2s[v,s],:], w3[v,:]) + b3[v] ----------------
__global__ __launch_bounds__(256)
void el_kernel(const int* __restrict__ w2s, const float* __restrict__ hP,
               const float* __restrict__ w3, const float* __restrict__ b3,
               float* __restrict__ el_g, unsigned int* __restrict__ vmask)
{
  int v = blockIdx.x;
  __shared__ float w3v[NH];
  __shared__ int crow[NS];
  int tid = threadIdx.x;
  if (tid < NS) crow[tid] = w2s[(size_t)v * NS + tid];
  for (int e = tid; e < NH; e += 256) w3v[e] = w3[(size_t)v * NH + e];
  __syncthreads();
  if (tid < 64) {
    bool valid = false;
    if (tid < NS) {
      valid = true;
      int c = crow[tid];
      for (int s2 = 0; s2 < tid; ++s2) if (crow[s2] == c) { valid = false; break; }
    }
    unsigned long long bal = __ballot(valid);
    if (tid == 0) vmask[v] = (unsigned int)(bal & 0xffffffffull);
  }
  int wave = tid >> 6, lane = tid & 63;
  float b3v = b3[v];
  #pragma unroll
  for (int q = 0; q < 8; ++q) {
    int s = wave * 8 + q;
    int c = crow[s];
    const float* hrow = hP + (size_t)c * NH;
    float acc = 0.f;
    #pragma unroll
    for (int e = 0; e < 8; ++e) acc += hrow[lane + e*64] * w3v[lane + e*64];
    acc = wredSum(acc);
    if (lane == 0) el_g[(size_t)v * NS + s] = acc + b3v;
  }
}

// ---------------- emission row-LSE via atomics (deterministic) ----------------
__global__ __launch_bounds__(256)
void init_e(int* __restrict__ emax, unsigned long long* __restrict__ esum)
{
  int i = blockIdx.x * 256 + threadIdx.x;
  if (i < NC) { emax[i] = 0x80000000; esum[i] = 0ull; }
}
__global__ __launch_bounds__(256)
void emit_max_k(const int* __restrict__ w2s, const float* __restrict__ el_g,
                const unsigned int* __restrict__ vmask, int* __restrict__ emax)
{
  int idx = blockIdx.x * 256 + threadIdx.x;   // over V*S
  int v = idx >> 5, s = idx & 31;
  if (!((vmask[v] >> s) & 1u)) return;
  atomicMax(&emax[w2s[idx]], f2ord(el_g[idx]));
}
__global__ __launch_bounds__(256)
void emit_sum_k(const int* __restrict__ w2s, const float* __restrict__ el_g,
                const unsigned int* __restrict__ vmask, const int* __restrict__ emax,
                unsigned long long* __restrict__ esum)
{
  int idx = blockIdx.x * 256 + threadIdx.x;
  int v = idx >> 5, s = idx & 31;
  if (!((vmask[v] >> s) & 1u)) return;
  int c = w2s[idx];
  float p = expf(el_g[idx] - ord2f(emax[c]));             // in (0,1]
  atomicAdd(&esum[c], (unsigned long long)(p * 0x1p40f)); // fixed-point, deterministic
}
__global__ __launch_bounds__(256)
void emit_fin_k(const int* __restrict__ emax, const unsigned long long* __restrict__ esum,
                float* __restrict__ lse_e)
{
  int c = blockIdx.x * 256 + threadIdx.x;
  if (c < NC) lse_e[c] = ord2f(emax[c]) + logf((float)esum[c] * 0x1p-40f);
}

// ---------------- forward-algorithm scan: one block per batch element ----------------
__global__ __launch_bounds__(1024)
void scan_kernel(const int* __restrict__ text, const int* __restrict__ w2s,
                 const float* __restrict__ tl, const float* __restrict__ lse_t,
                 const float* __restrict__ sv, const float* __restrict__ lse_st,
                 const float* __restrict__ el_g, const float* __restrict__ lse_e,
                 float* __restrict__ out_b)
{
  int b = blockIdx.x;
  __shared__ unsigned short cs[NT][NS];   // 16 KB
  __shared__ float D[NT][NS];             // 32 KB
  __shared__ float beta[NS];
  __shared__ float alpha_out[NS];
  __shared__ int textb[NT];
  int tid = threadIdx.x;

  if (tid < NT) textb[tid] = text[b * NT + tid];
  __syncthreads();
  for (int idx = tid; idx < NT * NS; idx += 1024) {
    int t = idx >> 5, s = idx & 31;
    int v = textb[t];
    int c = w2s[v * NS + s];
    cs[t][s] = (unsigned short)c;
    D[t][s] = el_g[(size_t)v * NS + s] - lse_e[c] - lse_t[c];
  }
  __syncthreads();
  if (tid < NS) {
    int c0 = cs[0][tid];
    beta[tid] = sv[c0] - lse_st[0] + D[0][tid];   // (init + obs0 - lse_t) folded
  }
  __syncthreads();

  const int j = tid >> 5, i = tid & 31;
  float val_next = tl[(size_t)cs[0][i] * NC + cs[1][j]];
  for (int t = 0; t < NT - 1; ++t) {
    float val = val_next;
    if (t < NT - 2) val_next = tl[(size_t)cs[t+1][i] * NC + cs[t+2][j]]; // prefetch
    float x = val + beta[i];
    float m = x;
    #pragma unroll
    for (int o = 16; o; o >>= 1) m = fmaxf(m, __shfl_xor(m, o, 32));
    float p = expf(x - m);
    #pragma unroll
    for (int o = 16; o; o >>= 1) p += __shfl_xor(p, o, 32);
    float r = m + logf(p);                       // LSE over i
    __syncthreads();
    if (i == 0) {
      if (t < NT - 2) beta[j] = r + D[t+1][j];
      else alpha_out[j] = r + D[t+1][j] + lse_t[cs[t+1][j]];
    }
    __syncthreads();
  }

  if (tid < 32) {
    float a = alpha_out[tid];
    float m = a;
    #pragma unroll
    for (int o = 16; o; o >>= 1) m = fmaxf(m, __shfl_xor(m, o, 32));
    float p = expf(a - m);
    #pragma unroll
    for (int o = 16; o; o >>= 1) p += __shfl_xor(p, o, 32);
    if (tid == 0) out_b[b] = m + logf(p);
  }
}

__global__ void final_sum(const float* __restrict__ out_b, float* __restrict__ out)
{
  if (threadIdx.x == 0) {
    float s = 0.f;
    for (int b = 0; b < NB; ++b) s += out_b[b];
    out[0] = s;
  }
}

// ---------------- launch ----------------
extern "C" void kernel_launch(void* const* d_in, const int* in_sizes, int n_in,
                              void* d_out, int out_size, void* d_ws, size_t ws_size,
                              hipStream_t stream)
{
  (void)in_sizes; (void)n_in; (void)out_size; (void)ws_size;
  const int*   text      = (const int*)d_in[0];
  const int*   w2s       = (const int*)d_in[1];
  const float* start_emb = (const float*)d_in[2];
  const float* start_w1  = (const float*)d_in[3];
  const float* start_b1  = (const float*)d_in[4];
  const float* start_w2  = (const float*)d_in[5];
  const float* start_b2  = (const float*)d_in[6];
  const float* start_w3  = (const float*)d_in[7];
  const float* start_b3  = (const float*)d_in[8];
  const float* state_emb = (const float*)d_in[9];
  const float* trans_w1  = (const float*)d_in[10];
  const float* trans_b1  = (const float*)d_in[11];
  const float* trans_w2  = (const float*)d_in[12];
  const float* trans_b2  = (const float*)d_in[13];
  const float* nsp       = (const float*)d_in[14];
  const float* pre_emb   = (const float*)d_in[15];
  const float* term_w1   = (const float*)d_in[16];
  const float* term_b1   = (const float*)d_in[17];
  const float* term_w2   = (const float*)d_in[18];
  const float* term_b2   = (const float*)d_in[19];
  const float* term_w3   = (const float*)d_in[20];
  const float* term_b3   = (const float*)d_in[21];

  // workspace arena (~136.1 MB)
  float* tl    = (float*)d_ws;                 // 16,777,216 f  (64 MB)
  float* h1    = tl + 16777216;                // 2,097,152 f
  float* h2    = h1 + 2097152;                 // 2,097,152 f
  float* sv    = h2 + 2097152;                 // 4096
  float* lse_t = sv + NC;                      // 4096
  float* lse_e = lse_t + NC;                   // 4096
  float* lse_s = lse_e + NC;                   // 1 (pad 64)
  float* out_b = lse_s + 64;                   // 32 (pad 64)
  float* el_g  = out_b + 64;                   // 1,024,000 f
  unsigned int* vmask = (unsigned int*)(el_g + 1024000);         // 32,000 u32
  int* emax    = (int*)(vmask + 32000);                          // 4096 i32
  unsigned long long* esum = (unsigned long long*)(emax + 4096); // 4096 u64
  unsigned short* sE_s  = (unsigned short*)(esum + 4096);        // 4096x1024 u16 each:
  unsigned short* tE_s  = sE_s  + 4194304;
  unsigned short* pE_s  = tE_s  + 4194304;
  unsigned short* nsp_s = pE_s  + 4194304;
  unsigned short* h1_s  = nsp_s + 4194304;
  unsigned short* w1S_s = h1_s  + 4194304;     // 512x1024 u16 each:
  unsigned short* w2S_s = w1S_s + 524288;
  unsigned short* w1T_s = w2S_s + 524288;
  unsigned short* w2T_s = w1T_s + 524288;
  unsigned short* w1P_s = w2T_s + 524288;
  unsigned short* w2P_s = w1P_s + 524288;
  unsigned short* h2t_s = sE_s;                // alias: start GEMM1 done before trans h2 split

  // ---- upfront split conversions (10 matrices, one launch) ----
  ConvArgs ca;
  ca.src[0]=start_emb; ca.dst[0]=sE_s;  ca.rows[0]=NC;
  ca.src[1]=state_emb; ca.dst[1]=tE_s;  ca.rows[1]=NC;
  ca.src[2]=pre_emb;   ca.dst[2]=pE_s;  ca.rows[2]=NC;
  ca.src[3]=nsp;       ca.dst[3]=nsp_s; ca.rows[3]=NC;
  ca.src[4]=start_w1;  ca.dst[4]=w1S_s; ca.rows[4]=NH;
  ca.src[5]=start_w2;  ca.dst[5]=w2S_s; ca.rows[5]=NH;
  ca.src[6]=trans_w1;  ca.dst[6]=w1T_s; ca.rows[6]=NH;
  ca.src[7]=trans_w2;  ca.dst[7]=w2T_s; ca.rows[7]=NH;
  ca.src[8]=term_w1;   ca.dst[8]=w1P_s; ca.rows[8]=NH;
  ca.src[9]=term_w2;   ca.dst[9]=w2P_s; ca.rows[9]=NH;
  conv_batch<<<dim3(1024, 10), 256, 0, stream>>>(ca);

  dim3 blk(256);
  dim3 gHH(4, 64);    // BM=64 tiles: 4096/64 x 512/128
  dim3 gCC(32, 32);   // BM=128 tiles: 4096/128 x 4096/128

  // start branch
  gemm_bf16s<64, true,  true,  false><<<gHH, blk, 0, stream>>>(sE_s, w1S_s, start_b1, nullptr,   h1, NC, NH, NH);
  conv_single<<<1024, 256, 0, stream>>>(h1, h1_s);
  gemm_bf16s<64, true,  true,  true ><<<gHH, blk, 0, stream>>>(h1_s, w2S_s, start_b2, start_emb, h2, NC, NH, NH);
  dot_head<<<NC, 64, 0, stream>>>(h2, start_w3, start_b3, sv);
  lse_vec<<<1, 1024, 0, stream>>>(sv, NC, lse_s);

  // transition branch
  gemm_bf16s<64, true,  true,  false><<<gHH, blk, 0, stream>>>(tE_s, w1T_s, trans_b1, nullptr,   h1, NC, NH, NH);
  conv_single<<<1024, 256, 0, stream>>>(h1, h1_s);
  gemm_bf16s<64, true,  true,  true ><<<gHH, blk, 0, stream>>>(h1_s, w2T_s, trans_b2, state_emb, h2, NC, NH, NH);
  conv_single<<<1024, 256, 0, stream>>>(h2, h2t_s);
  gemm_bf16s<128, false, false, false><<<gCC, blk, 0, stream>>>(h2t_s, nsp_s, nullptr, nullptr, tl, NC, NC, NH);
  row_lse_trans<<<NC, 256, 0, stream>>>(tl, lse_t);

  // emission branch
  gemm_bf16s<64, true,  true,  false><<<gHH, blk, 0, stream>>>(pE_s, w1P_s, term_b1, nullptr,  h1, NC, NH, NH);
  conv_single<<<1024, 256, 0, stream>>>(h1, h1_s);
  gemm_bf16s<64, true,  true,  true ><<<gHH, blk, 0, stream>>>(h1_s, w2P_s, term_b2, pre_emb,  h2, NC, NH, NH);
  el_kernel<<<NV, 256, 0, stream>>>(w2s, h2, term_w3, term_b3, el_g, vmask);
  init_e<<<16, 256, 0, stream>>>(emax, esum);
  emit_max_k<<<NV * NS / 256, 256, 0, stream>>>(w2s, el_g, vmask, emax);
  emit_sum_k<<<NV * NS / 256, 256, 0, stream>>>(w2s, el_g, vmask, emax, esum);
  emit_fin_k<<<NC / 256, 256, 0, stream>>>(emax, esum, lse_e);

  // scan + final
  scan_kernel<<<NB, 1024, 0, stream>>>(text, w2s, tl, lse_t, sv, lse_s, el_g, lse_e, out_b);
  final_sum<<<1, 64, 0, stream>>>(out_b, (float*)d_out);
}

// Round 3
// 959.550 us; speedup vs baseline: 1.1022x; 1.1022x over previous
//
#include <hip/hip_runtime.h>
#include <hip/hip_bf16.h>
#include <math.h>

// Problem dims
#define NV 32000
#define NC 4096
#define NS 32
#define NH 512
#define NB 32
#define NT 256

typedef short s16x8 __attribute__((ext_vector_type(8)));
typedef float f32x4 __attribute__((ext_vector_type(4)));

// ---------------- helpers ----------------
__device__ __forceinline__ float wredMax(float v){
  #pragma unroll
  for (int o = 32; o; o >>= 1) v = fmaxf(v, __shfl_xor(v, o, 64));
  return v;
}
__device__ __forceinline__ float wredSum(float v){
  #pragma unroll
  for (int o = 32; o; o >>= 1) v += __shfl_xor(v, o, 64);
  return v;
}
// order-preserving float<->int for atomicMax (no NaN/Inf in inputs)
__device__ __forceinline__ int f2ord(float f){ int i = __float_as_int(f); return i >= 0 ? i : (i ^ 0x7fffffff); }
__device__ __forceinline__ float ord2f(int i){ return __int_as_float(i >= 0 ? i : (i ^ 0x7fffffff)); }

// f32 -> bf16 round-nearest-even (bit trick; inputs are well-behaved, no NaN/Inf)
__device__ __forceinline__ unsigned short f2bf(float x){
  unsigned int u = __float_as_uint(x);
  return (unsigned short)((u + 0x7fffu + ((u >> 16) & 1u)) >> 16);
}
__device__ __forceinline__ float bf2f(unsigned short h){
  return __uint_as_float((unsigned int)h << 16);
}

// ---------------- split conversion: f32 [R][512] -> bf16 [R][1024] = [hi(512) | lo(512)] ----------------
__device__ __forceinline__ void conv_body(const float* __restrict__ src,
                                          unsigned short* __restrict__ dst, int idx)
{
  const float* s = src + (size_t)idx * 8;
  float4 f0 = *(const float4*)s;
  float4 f1 = *(const float4*)(s + 4);
  float fv[8] = {f0.x, f0.y, f0.z, f0.w, f1.x, f1.y, f1.z, f1.w};
  s16x8 vh, vl;
  #pragma unroll
  for (int e = 0; e < 8; ++e) {
    unsigned short h = f2bf(fv[e]);
    vh[e] = (short)h;
    vl[e] = (short)f2bf(fv[e] - bf2f(h));
  }
  int r = idx >> 6, c8 = idx & 63;           // 64 8-elem groups per row (K=512)
  unsigned short* d = dst + (size_t)r * 1024 + c8 * 8;
  *(s16x8*)d = vh;
  *(s16x8*)(d + 512) = vl;
}

struct ConvArgs {
  const float* src[10];
  unsigned short* dst[10];
  int rows[10];
};

__global__ __launch_bounds__(256)
void conv_batch(ConvArgs a)
{
  int z = blockIdx.y;
  int idx = blockIdx.x * 256 + threadIdx.x;
  if (idx >= a.rows[z] * 64) return;
  conv_body(a.src[z], a.dst[z], idx);
}

__global__ __launch_bounds__(256)
void conv_single(const float* __restrict__ src, unsigned short* __restrict__ dst)
{
  int idx = blockIdx.x * 256 + threadIdx.x;   // grid sized exactly: 4096*64/256 blocks
  conv_body(src, dst, idx);
}

// ---------------- split-bf16 MFMA NT GEMM ----------------
// C[m,n] = act( sum_k A[m,k]*B[n,k] (+bias[n]) (+res[m,n]) ) via 3 bf16 products:
// Ahi*Bhi + Alo*Bhi + Ahi*Blo. A,B split as [hi(K)|lo(K)], row stride 2K.
// Tile BM x 128, BK=64, 256 threads = 4 waves (2x2), MFMA 16x16x32 bf16.
// LDS XOR-swizzle: byte ^= (row&7)<<4 on both write and read -> conflict-free.
template<int BM, bool RELU, bool BIAS, bool RES>
__global__ __launch_bounds__(256)
void gemm_bf16s(const unsigned short* __restrict__ Asp, const unsigned short* __restrict__ Bsp,
                const float* __restrict__ bias, const float* __restrict__ res,
                float* __restrict__ Co, int M, int N, int K)
{
  constexpr int BN = 128;
  constexpr int MF = BM / 32;     // A frags per wave
  constexpr int NFR = 4;          // B frags per wave
  __shared__ char smem[BM * 128 + BN * 128];
  char* smA = smem;
  char* smB = smem + BM * 128;

  const int tid  = threadIdx.x;
  const int lane = tid & 63, w = tid >> 6;
  const int wr = w >> 1, wc = w & 1;
  const int bm = blockIdx.y * BM, bn = blockIdx.x * BN;
  const int lda = 2 * K;
  const int l8 = lane >> 3, s8 = lane & 7;
  const int frow = lane & 15, kgrp = lane >> 4;

  f32x4 acc[MF][NFR] = {};

  #pragma unroll 1
  for (int seg = 0; seg < 3; ++seg) {
    const int aoff = (seg == 1) ? K : 0;
    const int boff = (seg == 2) ? K : 0;
    #pragma unroll 1
    for (int k0 = 0; k0 < K; k0 += 64) {
      #pragma unroll
      for (int c = 0; c < MF; ++c) {
        int q = w * MF + c;
        int row = q * 8 + l8;
        s16x8 v = *(const s16x8*)(Asp + (size_t)(bm + row) * lda + aoff + k0 + s8 * 8);
        unsigned int o = (unsigned int)(row * 128 + (s8 << 4));
        o ^= (unsigned int)((row & 7) << 4);
        *(s16x8*)(smA + o) = v;
      }
      #pragma unroll
      for (int c = 0; c < NFR; ++c) {
        int q = w * NFR + c;
        int row = q * 8 + l8;
        s16x8 v = *(const s16x8*)(Bsp + (size_t)(bn + row) * lda + boff + k0 + s8 * 8);
        unsigned int o = (unsigned int)(row * 128 + (s8 << 4));
        o ^= (unsigned int)((row & 7) << 4);
        *(s16x8*)(smB + o) = v;
      }
      __syncthreads();
      #pragma unroll
      for (int kk = 0; kk < 64; kk += 32) {
        s16x8 af[MF], bfr[NFR];
        #pragma unroll
        for (int im = 0; im < MF; ++im) {
          int ar = wr * (BM / 2) + im * 16 + frow;
          unsigned int o = ((unsigned int)(ar * 128 + (kk + kgrp * 8) * 2)) ^ ((unsigned int)((ar & 7) << 4));
          af[im] = *(const s16x8*)(smA + o);
        }
        #pragma unroll
        for (int jn = 0; jn < NFR; ++jn) {
          int bc = wc * 64 + jn * 16 + frow;
          unsigned int o = ((unsigned int)(bc * 128 + (kk + kgrp * 8) * 2)) ^ ((unsigned int)((bc & 7) << 4));
          bfr[jn] = *(const s16x8*)(smB + o);
        }
        #pragma unroll
        for (int im = 0; im < MF; ++im)
          #pragma unroll
          for (int jn = 0; jn < NFR; ++jn)
            asm volatile("v_mfma_f32_16x16x32_bf16 %0, %1, %2, %0"
                         : "+v"(acc[im][jn]) : "v"(af[im]), "v"(bfr[jn]));
      }
      __syncthreads();
    }
  }
  asm volatile("s_nop 7\n\ts_nop 7" ::: );
  #pragma unroll
  for (int im = 0; im < MF; ++im) {
    int row0 = bm + wr * (BM / 2) + im * 16 + kgrp * 4;
    #pragma unroll
    for (int jn = 0; jn < NFR; ++jn) {
      int col = bn + wc * 64 + jn * 16 + frow;
      #pragma unroll
      for (int j = 0; j < 4; ++j) {
        int r = row0 + j;
        float v = acc[im][jn][j];
        if constexpr (BIAS) v += bias[col];
        if constexpr (RES)  v += res[(size_t)r * N + col];
        if constexpr (RELU) v = fmaxf(v, 0.f);
        Co[(size_t)r * N + col] = v;
      }
    }
  }
}

// ---------------- start head ----------------
__global__ __launch_bounds__(64)
void dot_head(const float* __restrict__ hS, const float* __restrict__ w3,
              const float* __restrict__ b3, float* __restrict__ sv)
{
  int c = blockIdx.x, lane = threadIdx.x;
  const float* hrow = hS + (size_t)c * NH;
  float acc = 0.f;
  #pragma unroll
  for (int e = 0; e < 8; ++e) acc += hrow[lane + e*64] * w3[lane + e*64];
  acc = wredSum(acc);
  if (lane == 0) sv[c] = acc + b3[0];
}

// ---------------- logsumexp over a length-n vector (single block) ----------------
__global__ __launch_bounds__(1024)
void lse_vec(const float* __restrict__ x, int n, float* __restrict__ out)
{
  int tid = threadIdx.x;
  __shared__ float sm[16], ss[16];
  float m = -INFINITY;
  for (int i = tid; i < n; i += 1024) m = fmaxf(m, x[i]);
  m = wredMax(m);
  if ((tid & 63) == 0) sm[tid >> 6] = m;
  __syncthreads();
  m = sm[0];
  #pragma unroll
  for (int wv = 1; wv < 16; ++wv) m = fmaxf(m, sm[wv]);
  float s = 0.f;
  for (int i = tid; i < n; i += 1024) s += expf(x[i] - m);
  s = wredSum(s);
  if ((tid & 63) == 0) ss[tid >> 6] = s;
  __syncthreads();
  if (tid == 0) {
    float tot = 0.f;
    #pragma unroll
    for (int wv = 0; wv < 16; ++wv) tot += ss[wv];
    out[0] = m + logf(tot);
  }
}

// ---------------- per-row LSE of tl over cols 0..NC-2 ----------------
__global__ __launch_bounds__(256)
void row_lse_trans(const float* __restrict__ tl, float* __restrict__ lse_t)
{
  int c = blockIdx.x;
  const float* row = tl + (size_t)c * NC;
  int tid = threadIdx.x;
  __shared__ float sm[4], ss[4];
  float m = -INFINITY;
  for (int n = tid; n < NC - 1; n += 256) m = fmaxf(m, row[n]);
  m = wredMax(m);
  if ((tid & 63) == 0) sm[tid >> 6] = m;
  __syncthreads();
  m = fmaxf(fmaxf(sm[0], sm[1]), fmaxf(sm[2], sm[3]));
  float s = 0.f;
  for (int n = tid; n < NC - 1; n += 256) s += expf(row[n] - m);
  s = wredSum(s);
  if ((tid & 63) == 0) ss[tid >> 6] = s;
  __syncthreads();
  if (tid == 0) lse_t[c] = m + logf(ss[0] + ss[1] + ss[2] + ss[3]);
}

// ---------------- emission gathered logits ----------------
__global__ __launch_bounds__(256)
void el_kernel(const int* __restrict__ w2s, const float* __restrict__ hP,
               const float* __restrict__ w3, const float* __restrict__ b3,
               float* __restrict__ el_g, unsigned int* __restrict__ vmask)
{
  int v = blockIdx.x;
  __shared__ float w3v[NH];
  __shared__ int crow[NS];
  int tid = threadIdx.x;
  if (tid < NS) crow[tid] = w2s[(size_t)v * NS + tid];
  for (int e = tid; e < NH; e += 256) w3v[e] = w3[(size_t)v * NH + e];
  __syncthreads();
  if (tid < 64) {
    bool valid = false;
    if (tid < NS) {
      valid = true;
      int c = crow[tid];
      for (int s2 = 0; s2 < tid; ++s2) if (crow[s2] == c) { valid = false; break; }
    }
    unsigned long long bal = __ballot(valid);
    if (tid == 0) vmask[v] = (unsigned int)(bal & 0xffffffffull);
  }
  int wave = tid >> 6, lane = tid & 63;
  float b3v = b3[v];
  #pragma unroll
  for (int q = 0; q < 8; ++q) {
    int s = wave * 8 + q;
    int c = crow[s];
    const float* hrow = hP + (size_t)c * NH;
    float acc = 0.f;
    #pragma unroll
    for (int e = 0; e < 8; ++e) acc += hrow[lane + e*64] * w3v[lane + e*64];
    acc = wredSum(acc);
    if (lane == 0) el_g[(size_t)v * NS + s] = acc + b3v;
  }
}

// ---------------- emission row-LSE via atomics (deterministic) ----------------
__global__ __launch_bounds__(256)
void init_e(int* __restrict__ emax, unsigned long long* __restrict__ esum)
{
  int i = blockIdx.x * 256 + threadIdx.x;
  if (i < NC) { emax[i] = 0x80000000; esum[i] = 0ull; }
}
__global__ __launch_bounds__(256)
void emit_max_k(const int* __restrict__ w2s, const float* __restrict__ el_g,
                const unsigned int* __restrict__ vmask, int* __restrict__ emax)
{
  int idx = blockIdx.x * 256 + threadIdx.x;   // over V*S
  int v = idx >> 5, s = idx & 31;
  if (!((vmask[v] >> s) & 1u)) return;
  atomicMax(&emax[w2s[idx]], f2ord(el_g[idx]));
}
__global__ __launch_bounds__(256)
void emit_sum_k(const int* __restrict__ w2s, const float* __restrict__ el_g,
                const unsigned int* __restrict__ vmask, const int* __restrict__ emax,
                unsigned long long* __restrict__ esum)
{
  int idx = blockIdx.x * 256 + threadIdx.x;
  int v = idx >> 5, s = idx & 31;
  if (!((vmask[v] >> s) & 1u)) return;
  int c = w2s[idx];
  float p = expf(el_g[idx] - ord2f(emax[c]));             // in (0,1]
  atomicAdd(&esum[c], (unsigned long long)(p * 0x1p40f)); // fixed-point, deterministic
}
__global__ __launch_bounds__(256)
void emit_fin_k(const int* __restrict__ emax, const unsigned long long* __restrict__ esum,
                float* __restrict__ lse_e)
{
  int c = blockIdx.x * 256 + threadIdx.x;
  if (c < NC) lse_e[c] = ord2f(emax[c]) + logf((float)esum[c] * 0x1p-40f);
}

// ---------------- cs precompute: cs_all[b][t][s] = w2s[text[b][t]][s] ----------------
__global__ __launch_bounds__(256)
void build_cs(const int* __restrict__ text, const int* __restrict__ w2s,
              unsigned short* __restrict__ cs_all)
{
  int idx = blockIdx.x * 256 + threadIdx.x;   // < NB*NT*NS = 262144
  int s = idx & 31;
  int bt = idx >> 5;
  int v = text[bt];
  cs_all[idx] = (unsigned short)w2s[(size_t)v * NS + s];
}

// ---------------- full-device gather of scan potentials ----------------
// pot[b][t][j*32+i] = tl[cs[b][t][i] * NC + cs[b][t+1][j]]
// Lane groups of 32 read 32 scattered cols of ONE tl row (same DRAM page region).
__global__ __launch_bounds__(1024)
void gather_pot(const unsigned short* __restrict__ cs_all, const float* __restrict__ tl,
                float* __restrict__ pot)
{
  int t = blockIdx.x;          // 0..NT-2
  int b = blockIdx.y;
  int tid = threadIdx.x;
  __shared__ unsigned short c1s[NS], c2s[NS];
  if (tid < NS) c1s[tid] = cs_all[((size_t)b * NT + t) * NS + tid];
  else if (tid < 2 * NS) c2s[tid - NS] = cs_all[((size_t)b * NT + t + 1) * NS + (tid - NS)];
  __syncthreads();
  int gi = tid >> 5, gj = tid & 31;           // gi: row index, gj: col index
  float v = tl[(size_t)c1s[gi] * NC + c2s[gj]];
  pot[((size_t)b * (NT - 1) + t) * 1024 + gj * 32 + gi] = v;
}

// ---------------- forward-algorithm scan (reads packed pot) ----------------
__global__ __launch_bounds__(1024)
void scan_kernel(const int* __restrict__ text, const int* __restrict__ w2s,
                 const float* __restrict__ pot, const float* __restrict__ lse_t,
                 const float* __restrict__ sv, const float* __restrict__ lse_st,
                 const float* __restrict__ el_g, const float* __restrict__ lse_e,
                 float* __restrict__ out_b)
{
  int b = blockIdx.x;
  __shared__ unsigned short cs[NT][NS];   // 16 KB
  __shared__ float D[NT][NS];             // 32 KB
  __shared__ float beta[NS];
  __shared__ float alpha_out[NS];
  __shared__ int textb[NT];
  int tid = threadIdx.x;

  if (tid < NT) textb[tid] = text[b * NT + tid];
  __syncthreads();
  for (int idx = tid; idx < NT * NS; idx += 1024) {
    int t = idx >> 5, s = idx & 31;
    int v = textb[t];
    int c = w2s[v * NS + s];
    cs[t][s] = (unsigned short)c;
    D[t][s] = el_g[(size_t)v * NS + s] - lse_e[c] - lse_t[c];
  }
  __syncthreads();
  if (tid < NS) {
    int c0 = cs[0][tid];
    beta[tid] = sv[c0] - lse_st[0] + D[0][tid];   // (init + obs0 - lse_t) folded
  }
  __syncthreads();

  const int j = tid >> 5, i = tid & 31;
  const float* potb = pot + (size_t)b * (NT - 1) * 1024;
  float val_next = potb[tid];
  for (int t = 0; t < NT - 1; ++t) {
    float val = val_next;
    if (t < NT - 2) val_next = potb[(size_t)(t + 1) * 1024 + tid];  // coalesced prefetch
    float x = val + beta[i];
    float m = x;
    #pragma unroll
    for (int o = 16; o; o >>= 1) m = fmaxf(m, __shfl_xor(m, o, 32));
    float p = expf(x - m);
    #pragma unroll
    for (int o = 16; o; o >>= 1) p += __shfl_xor(p, o, 32);
    float r = m + logf(p);                       // LSE over i
    __syncthreads();
    if (i == 0) {
      if (t < NT - 2) beta[j] = r + D[t+1][j];
      else alpha_out[j] = r + D[t+1][j] + lse_t[cs[t+1][j]];
    }
    __syncthreads();
  }

  if (tid < 32) {
    float a = alpha_out[tid];
    float m = a;
    #pragma unroll
    for (int o = 16; o; o >>= 1) m = fmaxf(m, __shfl_xor(m, o, 32));
    float p = expf(a - m);
    #pragma unroll
    for (int o = 16; o; o >>= 1) p += __shfl_xor(p, o, 32);
    if (tid == 0) out_b[b] = m + logf(p);
  }
}

__global__ void final_sum(const float* __restrict__ out_b, float* __restrict__ out)
{
  if (threadIdx.x == 0) {
    float s = 0.f;
    for (int b = 0; b < NB; ++b) s += out_b[b];
    out[0] = s;
  }
}

// ---------------- launch ----------------
extern "C" void kernel_launch(void* const* d_in, const int* in_sizes, int n_in,
                              void* d_out, int out_size, void* d_ws, size_t ws_size,
                              hipStream_t stream)
{
  (void)in_sizes; (void)n_in; (void)out_size; (void)ws_size;
  const int*   text      = (const int*)d_in[0];
  const int*   w2s       = (const int*)d_in[1];
  const float* start_emb = (const float*)d_in[2];
  const float* start_w1  = (const float*)d_in[3];
  const float* start_b1  = (const float*)d_in[4];
  const float* start_w2  = (const float*)d_in[5];
  const float* start_b2  = (const float*)d_in[6];
  const float* start_w3  = (const float*)d_in[7];
  const float* start_b3  = (const float*)d_in[8];
  const float* state_emb = (const float*)d_in[9];
  const float* trans_w1  = (const float*)d_in[10];
  const float* trans_b1  = (const float*)d_in[11];
  const float* trans_w2  = (const float*)d_in[12];
  const float* trans_b2  = (const float*)d_in[13];
  const float* nsp       = (const float*)d_in[14];
  const float* pre_emb   = (const float*)d_in[15];
  const float* term_w1   = (const float*)d_in[16];
  const float* term_b1   = (const float*)d_in[17];
  const float* term_w2   = (const float*)d_in[18];
  const float* term_b2   = (const float*)d_in[19];
  const float* term_w3   = (const float*)d_in[20];
  const float* term_b3   = (const float*)d_in[21];

  // workspace arena (~137 MB)
  float* tl    = (float*)d_ws;                 // 16,777,216 f  (64 MB)
  float* h1    = tl + 16777216;                // 2,097,152 f
  float* h2    = h1 + 2097152;                 // 2,097,152 f
  float* sv    = h2 + 2097152;                 // 4096
  float* lse_t = sv + NC;                      // 4096
  float* lse_e = lse_t + NC;                   // 4096
  float* lse_s = lse_e + NC;                   // 1 (pad 64)
  float* out_b = lse_s + 64;                   // 32 (pad 64)
  float* el_g  = out_b + 64;                   // 1,024,000 f
  unsigned int* vmask = (unsigned int*)(el_g + 1024000);         // 32,000 u32
  int* emax    = (int*)(vmask + 32000);                          // 4096 i32
  unsigned long long* esum = (unsigned long long*)(emax + 4096); // 4096 u64
  unsigned short* sE_s  = (unsigned short*)(esum + 4096);        // 4096x1024 u16 each:
  unsigned short* tE_s  = sE_s  + 4194304;
  unsigned short* pE_s  = tE_s  + 4194304;
  unsigned short* nsp_s = pE_s  + 4194304;
  unsigned short* h1_s  = nsp_s + 4194304;
  unsigned short* w1S_s = h1_s  + 4194304;     // 512x1024 u16 each:
  unsigned short* w2S_s = w1S_s + 524288;
  unsigned short* w1T_s = w2S_s + 524288;
  unsigned short* w2T_s = w1T_s + 524288;
  unsigned short* w1P_s = w2T_s + 524288;
  unsigned short* w2P_s = w1P_s + 524288;
  unsigned short* cs_all = w2P_s + 524288;     // 262,144 u16 (512 KB)
  unsigned short* h2t_s = sE_s;                // alias: start GEMM done before trans h2 split
  float* pot = (float*)sE_s;                   // alias: 33.4 MB over sE_s..h1_s (free after GEMMs)

  // ---- upfront split conversions (10 matrices, one launch) ----
  ConvArgs ca;
  ca.src[0]=start_emb; ca.dst[0]=sE_s;  ca.rows[0]=NC;
  ca.src[1]=state_emb; ca.dst[1]=tE_s;  ca.rows[1]=NC;
  ca.src[2]=pre_emb;   ca.dst[2]=pE_s;  ca.rows[2]=NC;
  ca.src[3]=nsp;       ca.dst[3]=nsp_s; ca.rows[3]=NC;
  ca.src[4]=start_w1;  ca.dst[4]=w1S_s; ca.rows[4]=NH;
  ca.src[5]=start_w2;  ca.dst[5]=w2S_s; ca.rows[5]=NH;
  ca.src[6]=trans_w1;  ca.dst[6]=w1T_s; ca.rows[6]=NH;
  ca.src[7]=trans_w2;  ca.dst[7]=w2T_s; ca.rows[7]=NH;
  ca.src[8]=term_w1;   ca.dst[8]=w1P_s; ca.rows[8]=NH;
  ca.src[9]=term_w2;   ca.dst[9]=w2P_s; ca.rows[9]=NH;
  conv_batch<<<dim3(1024, 10), 256, 0, stream>>>(ca);

  dim3 blk(256);
  dim3 gHH(4, 64);    // BM=64 tiles
  dim3 gCC(32, 32);   // BM=128 tiles

  // start branch
  gemm_bf16s<64, true,  true,  false><<<gHH, blk, 0, stream>>>(sE_s, w1S_s, start_b1, nullptr,   h1, NC, NH, NH);
  conv_single<<<1024, 256, 0, stream>>>(h1, h1_s);
  gemm_bf16s<64, true,  true,  true ><<<gHH, blk, 0, stream>>>(h1_s, w2S_s, start_b2, start_emb, h2, NC, NH, NH);
  dot_head<<<NC, 64, 0, stream>>>(h2, start_w3, start_b3, sv);
  lse_vec<<<1, 1024, 0, stream>>>(sv, NC, lse_s);

  // transition branch
  gemm_bf16s<64, true,  true,  false><<<gHH, blk, 0, stream>>>(tE_s, w1T_s, trans_b1, nullptr,   h1, NC, NH, NH);
  conv_single<<<1024, 256, 0, stream>>>(h1, h1_s);
  gemm_bf16s<64, true,  true,  true ><<<gHH, blk, 0, stream>>>(h1_s, w2T_s, trans_b2, state_emb, h2, NC, NH, NH);
  conv_single<<<1024, 256, 0, stream>>>(h2, h2t_s);
  gemm_bf16s<128, false, false, false><<<gCC, blk, 0, stream>>>(h2t_s, nsp_s, nullptr, nullptr, tl, NC, NC, NH);
  row_lse_trans<<<NC, 256, 0, stream>>>(tl, lse_t);

  // emission branch
  gemm_bf16s<64, true,  true,  false><<<gHH, blk, 0, stream>>>(pE_s, w1P_s, term_b1, nullptr,  h1, NC, NH, NH);
  conv_single<<<1024, 256, 0, stream>>>(h1, h1_s);
  gemm_bf16s<64, true,  true,  true ><<<gHH, blk, 0, stream>>>(h1_s, w2P_s, term_b2, pre_emb,  h2, NC, NH, NH);
  el_kernel<<<NV, 256, 0, stream>>>(w2s, h2, term_w3, term_b3, el_g, vmask);
  init_e<<<16, 256, 0, stream>>>(emax, esum);
  emit_max_k<<<NV * NS / 256, 256, 0, stream>>>(w2s, el_g, vmask, emax);
  emit_sum_k<<<NV * NS / 256, 256, 0, stream>>>(w2s, el_g, vmask, emax, esum);
  emit_fin_k<<<NC / 256, 256, 0, stream>>>(emax, esum, lse_e);

  // gather scan potentials at full-device parallelism (after all split-buffer users)
  build_cs<<<NB * NT * NS / 256, 256, 0, stream>>>(text, w2s, cs_all);
  gather_pot<<<dim3(NT - 1, NB), 1024, 0, stream>>>(cs_all, tl, pot);

  // scan + final
  scan_kernel<<<NB, 1024, 0, stream>>>(text, w2s, pot, lse_t, sv, lse_s, el_g, lse_e, out_b);
  final_sum<<<1, 64, 0, stream>>>(out_b, (float*)d_out);
}

// Round 5
// 899.050 us; speedup vs baseline: 1.1763x; 1.0673x over previous
//
#include <hip/hip_runtime.h>
#include <hip/hip_bf16.h>
#include <math.h>

// Problem dims
#define NV 32000
#define NC 4096
#define NS 32
#define NH 512
#define NB 32
#define NT 256

typedef short s16x8 __attribute__((ext_vector_type(8)));
typedef float f32x4 __attribute__((ext_vector_type(4)));

// ---------------- helpers ----------------
__device__ __forceinline__ float wredMax(float v){
  #pragma unroll
  for (int o = 32; o; o >>= 1) v = fmaxf(v, __shfl_xor(v, o, 64));
  return v;
}
__device__ __forceinline__ float wredSum(float v){
  #pragma unroll
  for (int o = 32; o; o >>= 1) v += __shfl_xor(v, o, 64);
  return v;
}
// order-preserving float<->int for atomicMax (no NaN/Inf in inputs)
__device__ __forceinline__ int f2ord(float f){ int i = __float_as_int(f); return i >= 0 ? i : (i ^ 0x7fffffff); }
__device__ __forceinline__ float ord2f(int i){ return __int_as_float(i >= 0 ? i : (i ^ 0x7fffffff)); }

// f32 -> bf16 round-nearest-even (bit trick; inputs are well-behaved, no NaN/Inf)
__device__ __forceinline__ unsigned short f2bf(float x){
  unsigned int u = __float_as_uint(x);
  return (unsigned short)((u + 0x7fffu + ((u >> 16) & 1u)) >> 16);
}
__device__ __forceinline__ float bf2f(unsigned short h){
  return __uint_as_float((unsigned int)h << 16);
}

// ---------------- split conversion: f32 [R][512] -> bf16 [R][1024] = [hi(512) | lo(512)] ----------------
__device__ __forceinline__ void conv_body(const float* __restrict__ src,
                                          unsigned short* __restrict__ dst, int idx)
{
  const float* s = src + (size_t)idx * 8;
  float4 f0 = *(const float4*)s;
  float4 f1 = *(const float4*)(s + 4);
  float fv[8] = {f0.x, f0.y, f0.z, f0.w, f1.x, f1.y, f1.z, f1.w};
  s16x8 vh, vl;
  #pragma unroll
  for (int e = 0; e < 8; ++e) {
    unsigned short h = f2bf(fv[e]);
    vh[e] = (short)h;
    vl[e] = (short)f2bf(fv[e] - bf2f(h));
  }
  int r = idx >> 6, c8 = idx & 63;           // 64 8-elem groups per row (K=512)
  unsigned short* d = dst + (size_t)r * 1024 + c8 * 8;
  *(s16x8*)d = vh;
  *(s16x8*)(d + 512) = vl;
}

struct ConvArgs {
  const float* src[10];
  unsigned short* dst[10];
  int rows[10];
};

__global__ __launch_bounds__(256)
void conv_batch(ConvArgs a)
{
  int z = blockIdx.y;
  int idx = blockIdx.x * 256 + threadIdx.x;
  if (idx >= a.rows[z] * 64) return;
  conv_body(a.src[z], a.dst[z], idx);
}

// ---------------- split-bf16 MFMA NT GEMM (C x C transition) ----------------
// C[m,n] = sum_k A[m,k]*B[n,k] via 3 bf16 products: Ahi*Bhi + Alo*Bhi + Ahi*Blo.
// A,B split as [hi(K)|lo(K)], row stride 2K. Tile BM x 128, BK=64, 4 waves (2x2).
// LDS XOR-swizzle: byte ^= (row&7)<<4 on write and read -> conflict-free.
template<int BM>
__global__ __launch_bounds__(256)
void gemm_bf16s(const unsigned short* __restrict__ Asp, const unsigned short* __restrict__ Bsp,
                float* __restrict__ Co, int M, int N, int K)
{
  constexpr int BN = 128;
  constexpr int MF = BM / 32;     // A frags per wave
  constexpr int NFR = 4;          // B frags per wave
  __shared__ char smem[BM * 128 + BN * 128];
  char* smA = smem;
  char* smB = smem + BM * 128;

  const int tid  = threadIdx.x;
  const int lane = tid & 63, w = tid >> 6;
  const int wr = w >> 1, wc = w & 1;
  const int bm = blockIdx.y * BM, bn = blockIdx.x * BN;
  const int lda = 2 * K;
  const int l8 = lane >> 3, s8 = lane & 7;
  const int frow = lane & 15, kgrp = lane >> 4;

  f32x4 acc[MF][NFR] = {};

  #pragma unroll 1
  for (int seg = 0; seg < 3; ++seg) {
    const int aoff = (seg == 1) ? K : 0;
    const int boff = (seg == 2) ? K : 0;
    #pragma unroll 1
    for (int k0 = 0; k0 < K; k0 += 64) {
      #pragma unroll
      for (int c = 0; c < MF; ++c) {
        int q = w * MF + c;
        int row = q * 8 + l8;
        s16x8 v = *(const s16x8*)(Asp + (size_t)(bm + row) * lda + aoff + k0 + s8 * 8);
        unsigned int o = (unsigned int)(row * 128 + (s8 << 4));
        o ^= (unsigned int)((row & 7) << 4);
        *(s16x8*)(smA + o) = v;
      }
      #pragma unroll
      for (int c = 0; c < NFR; ++c) {
        int q = w * NFR + c;
        int row = q * 8 + l8;
        s16x8 v = *(const s16x8*)(Bsp + (size_t)(bn + row) * lda + boff + k0 + s8 * 8);
        unsigned int o = (unsigned int)(row * 128 + (s8 << 4));
        o ^= (unsigned int)((row & 7) << 4);
        *(s16x8*)(smB + o) = v;
      }
      __syncthreads();
      #pragma unroll
      for (int kk = 0; kk < 64; kk += 32) {
        s16x8 af[MF], bfr[NFR];
        #pragma unroll
        for (int im = 0; im < MF; ++im) {
          int ar = wr * (BM / 2) + im * 16 + frow;
          unsigned int o = ((unsigned int)(ar * 128 + (kk + kgrp * 8) * 2)) ^ ((unsigned int)((ar & 7) << 4));
          af[im] = *(const s16x8*)(smA + o);
        }
        #pragma unroll
        for (int jn = 0; jn < NFR; ++jn) {
          int bc = wc * 64 + jn * 16 + frow;
          unsigned int o = ((unsigned int)(bc * 128 + (kk + kgrp * 8) * 2)) ^ ((unsigned int)((bc & 7) << 4));
          bfr[jn] = *(const s16x8*)(smB + o);
        }
        #pragma unroll
        for (int im = 0; im < MF; ++im)
          #pragma unroll
          for (int jn = 0; jn < NFR; ++jn)
            asm volatile("v_mfma_f32_16x16x32_bf16 %0, %1, %2, %0"
                         : "+v"(acc[im][jn]) : "v"(af[im]), "v"(bfr[jn]));
      }
      __syncthreads();
    }
  }
  asm volatile("s_nop 7\n\ts_nop 7" ::: );
  #pragma unroll
  for (int im = 0; im < MF; ++im) {
    int row0 = bm + wr * (BM / 2) + im * 16 + kgrp * 4;
    #pragma unroll
    for (int jn = 0; jn < NFR; ++jn) {
      int col = bn + wc * 64 + jn * 16 + frow;
      #pragma unroll
      for (int j = 0; j < 4; ++j)
        Co[(size_t)(row0 + j) * N + col] = acc[im][jn][j];
    }
  }
}

// ---------------- z-batched H x H res-MLP GEMM (3 branches in one launch) ----------------
// C = relu(A @ B^T + bias (+res)); outputs: f32 (Cf[z]) and/or split bf16 (Cs[z]).
// M=4096, N=K=512, BM=64, BN=128, grid (4, 64, 3).
struct G3 {
  const unsigned short* A[3];
  const unsigned short* B[3];
  const float* bias[3];
  const float* res[3];
  float* Cf[3];
  unsigned short* Cs[3];
};

template<bool RES>
__global__ __launch_bounds__(256)
void gemm3(G3 a)
{
  constexpr int BM = 64, BN = 128, K = 512, N = 512;
  constexpr int MF = 2, NFR = 4;
  __shared__ char smem[BM * 128 + BN * 128];
  char* smA = smem;
  char* smB = smem + BM * 128;

  const int z = blockIdx.z;
  const unsigned short* Asp = a.A[z];
  const unsigned short* Bsp = a.B[z];
  const float* bias = a.bias[z];
  float* Cf = a.Cf[z];
  unsigned short* Cs = a.Cs[z];

  const int tid  = threadIdx.x;
  const int lane = tid & 63, w = tid >> 6;
  const int wr = w >> 1, wc = w & 1;
  const int bm = blockIdx.y * BM, bn = blockIdx.x * BN;
  const int lda = 2 * K;
  const int l8 = lane >> 3, s8 = lane & 7;
  const int frow = lane & 15, kgrp = lane >> 4;

  f32x4 acc[MF][NFR] = {};

  #pragma unroll 1
  for (int seg = 0; seg < 3; ++seg) {
    const int aoff = (seg == 1) ? K : 0;
    const int boff = (seg == 2) ? K : 0;
    #pragma unroll 1
    for (int k0 = 0; k0 < K; k0 += 64) {
      #pragma unroll
      for (int c = 0; c < MF; ++c) {
        int q = w * MF + c;
        int row = q * 8 + l8;
        s16x8 v = *(const s16x8*)(Asp + (size_t)(bm + row) * lda + aoff + k0 + s8 * 8);
        unsigned int o = (unsigned int)(row * 128 + (s8 << 4));
        o ^= (unsigned int)((row & 7) << 4);
        *(s16x8*)(smA + o) = v;
      }
      #pragma unroll
      for (int c = 0; c < NFR; ++c) {
        int q = w * NFR + c;
        int row = q * 8 + l8;
        s16x8 v = *(const s16x8*)(Bsp + (size_t)(bn + row) * lda + boff + k0 + s8 * 8);
        unsigned int o = (unsigned int)(row * 128 + (s8 << 4));
        o ^= (unsigned int)((row & 7) << 4);
        *(s16x8*)(smB + o) = v;
      }
      __syncthreads();
      #pragma unroll
      for (int kk = 0; kk < 64; kk += 32) {
        s16x8 af[MF], bfr[NFR];
        #pragma unroll
        for (int im = 0; im < MF; ++im) {
          int ar = wr * (BM / 2) + im * 16 + frow;
          unsigned int o = ((unsigned int)(ar * 128 + (kk + kgrp * 8) * 2)) ^ ((unsigned int)((ar & 7) << 4));
          af[im] = *(const s16x8*)(smA + o);
        }
        #pragma unroll
        for (int jn = 0; jn < NFR; ++jn) {
          int bc = wc * 64 + jn * 16 + frow;
          unsigned int o = ((unsigned int)(bc * 128 + (kk + kgrp * 8) * 2)) ^ ((unsigned int)((bc & 7) << 4));
          bfr[jn] = *(const s16x8*)(smB + o);
        }
        #pragma unroll
        for (int im = 0; im < MF; ++im)
          #pragma unroll
          for (int jn = 0; jn < NFR; ++jn)
            asm volatile("v_mfma_f32_16x16x32_bf16 %0, %1, %2, %0"
                         : "+v"(acc[im][jn]) : "v"(af[im]), "v"(bfr[jn]));
      }
      __syncthreads();
    }
  }
  asm volatile("s_nop 7\n\ts_nop 7" ::: );
  #pragma unroll
  for (int im = 0; im < MF; ++im) {
    int row0 = bm + wr * (BM / 2) + im * 16 + kgrp * 4;
    #pragma unroll
    for (int jn = 0; jn < NFR; ++jn) {
      int col = bn + wc * 64 + jn * 16 + frow;
      #pragma unroll
      for (int j = 0; j < 4; ++j) {
        int r = row0 + j;
        float v = acc[im][jn][j] + bias[col];
        if constexpr (RES) v += a.res[z][(size_t)r * N + col];
        v = fmaxf(v, 0.f);
        if (Cf) Cf[(size_t)r * N + col] = v;
        if (Cs) {
          unsigned short hi = f2bf(v);
          Cs[(size_t)r * 1024 + col] = hi;
          Cs[(size_t)r * 1024 + 512 + col] = f2bf(v - bf2f(hi));
        }
      }
    }
  }
}

// ---------------- start head ----------------
__global__ __launch_bounds__(64)
void dot_head(const float* __restrict__ hS, const float* __restrict__ w3,
              const float* __restrict__ b3, float* __restrict__ sv)
{
  int c = blockIdx.x, lane = threadIdx.x;
  const float* hrow = hS + (size_t)c * NH;
  float acc = 0.f;
  #pragma unroll
  for (int e = 0; e < 8; ++e) acc += hrow[lane + e*64] * w3[lane + e*64];
  acc = wredSum(acc);
  if (lane == 0) sv[c] = acc + b3[0];
}

// ---------------- logsumexp over a length-n vector (single block) ----------------
__global__ __launch_bounds__(1024)
void lse_vec(const float* __restrict__ x, int n, float* __restrict__ out)
{
  int tid = threadIdx.x;
  __shared__ float sm[16], ss[16];
  float m = -INFINITY;
  for (int i = tid; i < n; i += 1024) m = fmaxf(m, x[i]);
  m = wredMax(m);
  if ((tid & 63) == 0) sm[tid >> 6] = m;
  __syncthreads();
  m = sm[0];
  #pragma unroll
  for (int wv = 1; wv < 16; ++wv) m = fmaxf(m, sm[wv]);
  float s = 0.f;
  for (int i = tid; i < n; i += 1024) s += expf(x[i] - m);
  s = wredSum(s);
  if ((tid & 63) == 0) ss[tid >> 6] = s;
  __syncthreads();
  if (tid == 0) {
    float tot = 0.f;
    #pragma unroll
    for (int wv = 0; wv < 16; ++wv) tot += ss[wv];
    out[0] = m + logf(tot);
  }
}

// ---------------- per-row LSE of tl over cols 0..NC-2 ----------------
__global__ __launch_bounds__(256)
void row_lse_trans(const float* __restrict__ tl, float* __restrict__ lse_t)
{
  int c = blockIdx.x;
  const float* row = tl + (size_t)c * NC;
  int tid = threadIdx.x;
  __shared__ float sm[4], ss[4];
  float m = -INFINITY;
  for (int n = tid; n < NC - 1; n += 256) m = fmaxf(m, row[n]);
  m = wredMax(m);
  if ((tid & 63) == 0) sm[tid >> 6] = m;
  __syncthreads();
  m = fmaxf(fmaxf(sm[0], sm[1]), fmaxf(sm[2], sm[3]));
  float s = 0.f;
  for (int n = tid; n < NC - 1; n += 256) s += expf(row[n] - m);
  s = wredSum(s);
  if ((tid & 63) == 0) ss[tid >> 6] = s;
  __syncthreads();
  if (tid == 0) lse_t[c] = m + logf(ss[0] + ss[1] + ss[2] + ss[3]);
}

// ---------------- emission gathered logits ----------------
__global__ __launch_bounds__(256)
void el_kernel(const int* __restrict__ w2s, const float* __restrict__ hP,
               const float* __restrict__ w3, const float* __restrict__ b3,
               float* __restrict__ el_g, unsigned int* __restrict__ vmask)
{
  int v = blockIdx.x;
  __shared__ float w3v[NH];
  __shared__ int crow[NS];
  int tid = threadIdx.x;
  if (tid < NS) crow[tid] = w2s[(size_t)v * NS + tid];
  for (int e = tid; e < NH; e += 256) w3v[e] = w3[(size_t)v * NH + e];
  __syncthreads();
  if (tid < 64) {
    bool valid = false;
    if (tid < NS) {
      valid = true;
      int c = crow[tid];
      for (int s2 = 0; s2 < tid; ++s2) if (crow[s2] == c) { valid = false; break; }
    }
    unsigned long long bal = __ballot(valid);
    if (tid == 0) vmask[v] = (unsigned int)(bal & 0xffffffffull);
  }
  int wave = tid >> 6, lane = tid & 63;
  float b3v = b3[v];
  #pragma unroll
  for (int q = 0; q < 8; ++q) {
    int s = wave * 8 + q;
    int c = crow[s];
    const float* hrow = hP + (size_t)c * NH;
    float acc = 0.f;
    #pragma unroll
    for (int e = 0; e < 8; ++e) acc += hrow[lane + e*64] * w3v[lane + e*64];
    acc = wredSum(acc);
    if (lane == 0) el_g[(size_t)v * NS + s] = acc + b3v;
  }
}

// ---------------- emission row-LSE via atomics (deterministic) ----------------
__global__ __launch_bounds__(256)
void init_e(int* __restrict__ emax, unsigned long long* __restrict__ esum)
{
  int i = blockIdx.x * 256 + threadIdx.x;
  if (i < NC) { emax[i] = 0x80000000; esum[i] = 0ull; }
}
__global__ __launch_bounds__(256)
void emit_max_k(const int* __restrict__ w2s, const float* __restrict__ el_g,
                const unsigned int* __restrict__ vmask, int* __restrict__ emax)
{
  int idx = blockIdx.x * 256 + threadIdx.x;   // over V*S
  int v = idx >> 5, s = idx & 31;
  if (!((vmask[v] >> s) & 1u)) return;
  atomicMax(&emax[w2s[idx]], f2ord(el_g[idx]));
}
__global__ __launch_bounds__(256)
void emit_sum_k(const int* __restrict__ w2s, const float* __restrict__ el_g,
                const unsigned int* __restrict__ vmask, const int* __restrict__ emax,
                unsigned long long* __restrict__ esum)
{
  int idx = blockIdx.x * 256 + threadIdx.x;
  int v = idx >> 5, s = idx & 31;
  if (!((vmask[v] >> s) & 1u)) return;
  int c = w2s[idx];
  float p = expf(el_g[idx] - ord2f(emax[c]));             // in (0,1]
  atomicAdd(&esum[c], (unsigned long long)(p * 0x1p40f)); // fixed-point, deterministic
}
__global__ __launch_bounds__(256)
void emit_fin_k(const int* __restrict__ emax, const unsigned long long* __restrict__ esum,
                float* __restrict__ lse_e)
{
  int c = blockIdx.x * 256 + threadIdx.x;
  if (c < NC) lse_e[c] = ord2f(emax[c]) + logf((float)esum[c] * 0x1p-40f);
}

// ---------------- build_D: folded obs terms + cs_all + beta0 + Dlast ----------------
__global__ __launch_bounds__(256)
void build_D(const int* __restrict__ text, const int* __restrict__ w2s,
             const float* __restrict__ el_g, const float* __restrict__ lse_e,
             const float* __restrict__ lse_t, const float* __restrict__ sv,
             const float* __restrict__ lse_s,
             float* __restrict__ Dall, float* __restrict__ Dlast,
             float* __restrict__ beta0, unsigned short* __restrict__ cs_all)
{
  int idx = blockIdx.x * 256 + threadIdx.x;   // < NB*NT*NS
  int s = idx & 31;
  int bt = idx >> 5;
  int t = bt & (NT - 1);
  int b = bt >> 8;
  int v = text[bt];
  int c = w2s[(size_t)v * NS + s];
  cs_all[idx] = (unsigned short)c;
  float D = el_g[(size_t)v * NS + s] - lse_e[c] - lse_t[c];
  Dall[idx] = D;
  if (t == NT - 1) Dlast[b * NS + s] = D + lse_t[c];
  if (t == 0)      beta0[b * NS + s] = sv[c] - lse_s[0] + D;
}

// ---------------- full-device gather of scan potentials ----------------
// pot[b][t][j*32+i] = tl[cs[b][t][i] * NC + cs[b][t+1][j]]
__global__ __launch_bounds__(1024)
void gather_pot(const unsigned short* __restrict__ cs_all, const float* __restrict__ tl,
                float* __restrict__ pot)
{
  int t = blockIdx.x;          // 0..NT-2
  int b = blockIdx.y;
  int tid = threadIdx.x;
  __shared__ unsigned short c1s[NS], c2s[NS];
  if (tid < NS) c1s[tid] = cs_all[((size_t)b * NT + t) * NS + tid];
  else if (tid < 2 * NS) c2s[tid - NS] = cs_all[((size_t)b * NT + t + 1) * NS + (tid - NS)];
  __syncthreads();
  int gi = tid >> 5, gj = tid & 31;
  float v = tl[(size_t)c1s[gi] * NC + c2s[gj]];
  pot[((size_t)b * (NT - 1) + t) * 1024 + gj * 32 + gi] = v;
}

// ---------------- single-wave scan step: LSE over i of (pot[j][i] + beta[i]) ----------------
// Lane (j, h=lane>>5) holds 16 i-values [16h..16h+16). In-lane tree reduce + 1 cross-half shfl.
__device__ __forceinline__ float lse_step(float4 p0, float4 p1, float4 p2, float4 p3,
                                          float beta, int h16)
{
  float pv[16] = {p0.x,p0.y,p0.z,p0.w, p1.x,p1.y,p1.z,p1.w,
                  p2.x,p2.y,p2.z,p2.w, p3.x,p3.y,p3.z,p3.w};
  float xs[16];
  #pragma unroll
  for (int q = 0; q < 16; ++q)
    xs[q] = pv[q] + __shfl(beta, h16 + q, 64);   // beta[i] lives in lane i (lower half)
  float a[8];
  #pragma unroll
  for (int q = 0; q < 8; ++q) a[q] = fmaxf(xs[q], xs[q + 8]);
  float c4[4];
  #pragma unroll
  for (int q = 0; q < 4; ++q) c4[q] = fmaxf(a[q], a[q + 4]);
  float m = fmaxf(fmaxf(c4[0], c4[1]), fmaxf(c4[2], c4[3]));
  m = fmaxf(m, __shfl_xor(m, 32, 64));           // combine halves
  float e[8];
  #pragma unroll
  for (int q = 0; q < 8; ++q) e[q] = __expf(xs[q] - m) + __expf(xs[q + 8] - m);
  float s4[4];
  #pragma unroll
  for (int q = 0; q < 4; ++q) s4[q] = e[q] + e[q + 4];
  float st = (s4[0] + s4[1]) + (s4[2] + s4[3]);
  st += __shfl_xor(st, 32, 64);
  return m + __logf(st);
}

// ---------------- forward-algorithm scan: ONE WAVE per batch element, no barriers ----------------
__global__ __launch_bounds__(64)
void scan_kernel(const float* __restrict__ pot, const float* __restrict__ Dall,
                 const float* __restrict__ Dlast, const float* __restrict__ beta0,
                 float* __restrict__ out_b)
{
  const int b = blockIdx.x;
  const int lane = threadIdx.x;
  const int j = lane & 31;
  const int h16 = (lane >> 5) * 16;
  const float* potb = pot + (size_t)b * (NT - 1) * 1024 + j * 32 + h16;
  const float* Db = Dall + (size_t)b * NT * NS + j;

  float beta = beta0[b * NS + j];

  // depth-2 register double-buffer: A = even slices, B = odd slices
  float4 A0 = *(const float4*)(potb + 0);
  float4 A1 = *(const float4*)(potb + 4);
  float4 A2 = *(const float4*)(potb + 8);
  float4 A3 = *(const float4*)(potb + 12);
  const float* pB0 = potb + 1024;
  float4 B0 = *(const float4*)(pB0 + 0);
  float4 B1 = *(const float4*)(pB0 + 4);
  float4 B2 = *(const float4*)(pB0 + 8);
  float4 B3 = *(const float4*)(pB0 + 12);
  float dA = Db[1 * NS];
  float dB = Db[2 * NS];

  #pragma unroll 1
  for (int t = 0; t < NT - 2; t += 2) {        // t = 0,2,...,252
    // ---- even step t (slice t in A) ----
    float r = lse_step(A0, A1, A2, A3, beta, h16);
    beta = r + dA;
    const float* pn = potb + (size_t)(t + 2) * 1024;   // t+2 <= 254, always valid
    A0 = *(const float4*)(pn + 0);
    A1 = *(const float4*)(pn + 4);
    A2 = *(const float4*)(pn + 8);
    A3 = *(const float4*)(pn + 12);
    dA = Db[(t + 3 < NT ? t + 3 : NT - 1) * NS];
    // ---- odd step t+1 (slice t+1 in B) ----
    float r2 = lse_step(B0, B1, B2, B3, beta, h16);
    beta = r2 + dB;
    int tb = (t + 3 < NT - 1) ? t + 3 : NT - 2;        // clamp slice index to 254
    const float* pn2 = potb + (size_t)tb * 1024;
    B0 = *(const float4*)(pn2 + 0);
    B1 = *(const float4*)(pn2 + 4);
    B2 = *(const float4*)(pn2 + 8);
    B3 = *(const float4*)(pn2 + 12);
    dB = Db[(t + 4 < NT ? t + 4 : NT - 1) * NS];
  }
  // ---- final step t = 254 (slice 254 in A), un-fold lse_t via Dlast ----
  float r = lse_step(A0, A1, A2, A3, beta, h16);
  float rfin = r + Dlast[b * NS + j];

  // LSE over j within each 32-lane group (both halves identical)
  float m = rfin;
  #pragma unroll
  for (int o = 16; o; o >>= 1) m = fmaxf(m, __shfl_xor(m, o, 32));
  float p = expf(rfin - m);
  #pragma unroll
  for (int o = 16; o; o >>= 1) p += __shfl_xor(p, o, 32);
  if (lane == 0) out_b[b] = m + logf(p);
}

__global__ void final_sum(const float* __restrict__ out_b, float* __restrict__ out)
{
  if (threadIdx.x == 0) {
    float s = 0.f;
    for (int b = 0; b < NB; ++b) s += out_b[b];
    out[0] = s;
  }
}

// ---------------- launch ----------------
extern "C" void kernel_launch(void* const* d_in, const int* in_sizes, int n_in,
                              void* d_out, int out_size, void* d_ws, size_t ws_size,
                              hipStream_t stream)
{
  (void)in_sizes; (void)n_in; (void)out_size; (void)ws_size;
  const int*   text      = (const int*)d_in[0];
  const int*   w2s       = (const int*)d_in[1];
  const float* start_emb = (const float*)d_in[2];
  const float* start_w1  = (const float*)d_in[3];
  const float* start_b1  = (const float*)d_in[4];
  const float* start_w2  = (const float*)d_in[5];
  const float* start_b2  = (const float*)d_in[6];
  const float* start_w3  = (const float*)d_in[7];
  const float* start_b3  = (const float*)d_in[8];
  const float* state_emb = (const float*)d_in[9];
  const float* trans_w1  = (const float*)d_in[10];
  const float* trans_b1  = (const float*)d_in[11];
  const float* trans_w2  = (const float*)d_in[12];
  const float* trans_b2  = (const float*)d_in[13];
  const float* nsp       = (const float*)d_in[14];
  const float* pre_emb   = (const float*)d_in[15];
  const float* term_w1   = (const float*)d_in[16];
  const float* term_b1   = (const float*)d_in[17];
  const float* term_w2   = (const float*)d_in[18];
  const float* term_b2   = (const float*)d_in[19];
  const float* term_w3   = (const float*)d_in[20];
  const float* term_b3   = (const float*)d_in[21];

  // ---- workspace arena (136.45 MB; R3 proved >= 136.97 MB available) ----
  float* tl    = (float*)d_ws;                     // 16,777,216 f (64 MB)
  float* el_g  = tl + 16777216;                    // 1,024,000 f
  float* sv    = el_g + 1024000;                   // 4096
  float* lse_t = sv + 4096;                        // 4096
  float* lse_e = lse_t + 4096;                     // 4096
  float* lse_s = lse_e + 4096;                     // 64
  float* out_b = lse_s + 64;                       // 64
  float* Dlast = out_b + 64;                       // 1024
  float* beta0 = Dlast + 1024;                     // 1024
  unsigned int* vmask = (unsigned int*)(beta0 + 1024);            // 32,768 u32
  int* emax = (int*)(vmask + 32768);                              // 4096 i32
  unsigned long long* esum = (unsigned long long*)(emax + 4096);  // 4096 u64
  unsigned short* sE_s  = (unsigned short*)(esum + 4096);  // 4096x1024 u16 each:
  unsigned short* tE_s  = sE_s  + 4194304;
  unsigned short* pE_s  = tE_s  + 4194304;
  unsigned short* nsp_s = pE_s  + 4194304;
  unsigned short* w1S_s = nsp_s + 4194304;         // 512x1024 u16 each:
  unsigned short* w2S_s = w1S_s + 524288;
  unsigned short* w1T_s = w2S_s + 524288;
  unsigned short* w2T_s = w1T_s + 524288;
  unsigned short* w1P_s = w2T_s + 524288;
  unsigned short* w2P_s = w1P_s + 524288;
  unsigned short* h1s0  = w2P_s + 524288;          // 4096x1024 u16 each (split h1):
  unsigned short* h1s1  = h1s0 + 4194304;
  unsigned short* h1s2  = h1s1 + 4194304;
  // aliases (lifetime-disjoint):
  float* h2f0 = (float*)sE_s;        // start h2 f32  (sE dead after GEMM1)
  unsigned short* h2s1 = tE_s;       // trans h2 split (tE dead after GEMM1)
  float* h2f2 = (float*)pE_s;        // term h2 f32   (pE dead after GEMM1)
  float* pot  = (float*)sE_s;        // 8,355,840 f over sE..nsp (dead after heads/C×C)
  float* Dall = (float*)h1s0;        // 262,144 f (h1s dead after GEMM2)
  unsigned short* cs_all = (unsigned short*)((char*)h1s0 + 1048576);  // 262,144 u16

  // ---- upfront split conversions (10 matrices, one launch) ----
  ConvArgs ca;
  ca.src[0]=start_emb; ca.dst[0]=sE_s;  ca.rows[0]=NC;
  ca.src[1]=state_emb; ca.dst[1]=tE_s;  ca.rows[1]=NC;
  ca.src[2]=pre_emb;   ca.dst[2]=pE_s;  ca.rows[2]=NC;
  ca.src[3]=nsp;       ca.dst[3]=nsp_s; ca.rows[3]=NC;
  ca.src[4]=start_w1;  ca.dst[4]=w1S_s; ca.rows[4]=NH;
  ca.src[5]=start_w2;  ca.dst[5]=w2S_s; ca.rows[5]=NH;
  ca.src[6]=trans_w1;  ca.dst[6]=w1T_s; ca.rows[6]=NH;
  ca.src[7]=trans_w2;  ca.dst[7]=w2T_s; ca.rows[7]=NH;
  ca.src[8]=term_w1;   ca.dst[8]=w1P_s; ca.rows[8]=NH;
  ca.src[9]=term_w2;   ca.dst[9]=w2P_s; ca.rows[9]=NH;
  conv_batch<<<dim3(1024, 10), 256, 0, stream>>>(ca);

  // ---- z-batched res-MLP: GEMM1 (split out), GEMM2 (f32/split per branch) ----
  G3 g1;
  g1.A[0]=sE_s;  g1.A[1]=tE_s;  g1.A[2]=pE_s;
  g1.B[0]=w1S_s; g1.B[1]=w1T_s; g1.B[2]=w1P_s;
  g1.bias[0]=start_b1; g1.bias[1]=trans_b1; g1.bias[2]=term_b1;
  g1.res[0]=nullptr; g1.res[1]=nullptr; g1.res[2]=nullptr;
  g1.Cf[0]=nullptr; g1.Cf[1]=nullptr; g1.Cf[2]=nullptr;
  g1.Cs[0]=h1s0; g1.Cs[1]=h1s1; g1.Cs[2]=h1s2;
  gemm3<false><<<dim3(4, 64, 3), 256, 0, stream>>>(g1);

  G3 g2;
  g2.A[0]=h1s0;  g2.A[1]=h1s1;  g2.A[2]=h1s2;
  g2.B[0]=w2S_s; g2.B[1]=w2T_s; g2.B[2]=w2P_s;
  g2.bias[0]=start_b2; g2.bias[1]=trans_b2; g2.bias[2]=term_b2;
  g2.res[0]=start_emb; g2.res[1]=state_emb; g2.res[2]=pre_emb;
  g2.Cf[0]=h2f0; g2.Cf[1]=nullptr; g2.Cf[2]=h2f2;
  g2.Cs[0]=nullptr; g2.Cs[1]=h2s1; g2.Cs[2]=nullptr;
  gemm3<true><<<dim3(4, 64, 3), 256, 0, stream>>>(g2);

  // start head
  dot_head<<<NC, 64, 0, stream>>>(h2f0, start_w3, start_b3, sv);
  lse_vec<<<1, 1024, 0, stream>>>(sv, NC, lse_s);

  // transition C x C + row LSE
  gemm_bf16s<128><<<dim3(32, 32), 256, 0, stream>>>(h2s1, nsp_s, tl, NC, NC, NH);
  row_lse_trans<<<NC, 256, 0, stream>>>(tl, lse_t);

  // emission branch
  el_kernel<<<NV, 256, 0, stream>>>(w2s, h2f2, term_w3, term_b3, el_g, vmask);
  init_e<<<16, 256, 0, stream>>>(emax, esum);
  emit_max_k<<<NV * NS / 256, 256, 0, stream>>>(w2s, el_g, vmask, emax);
  emit_sum_k<<<NV * NS / 256, 256, 0, stream>>>(w2s, el_g, vmask, emax, esum);
  emit_fin_k<<<NC / 256, 256, 0, stream>>>(emax, esum, lse_e);

  // folded obs terms + full-device gather of scan potentials
  build_D<<<NB * NT * NS / 256, 256, 0, stream>>>(text, w2s, el_g, lse_e, lse_t, sv, lse_s,
                                                  Dall, Dlast, beta0, cs_all);
  gather_pot<<<dim3(NT - 1, NB), 1024, 0, stream>>>(cs_all, tl, pot);

  // scan + final
  scan_kernel<<<NB, 64, 0, stream>>>(pot, Dall, Dlast, beta0, out_b);
  final_sum<<<1, 64, 0, stream>>>(out_b, (float*)d_out);
}

// Round 8
// 879.348 us; speedup vs baseline: 1.2027x; 1.0224x over previous
//
#include <hip/hip_runtime.h>
#include <hip/hip_bf16.h>
#include <math.h>

// Problem dims
#define NV 32000
#define NC 4096
#define NS 32
#define NH 512
#define NB 32
#define NT 256

typedef short s16x8 __attribute__((ext_vector_type(8)));
typedef float f32x4 __attribute__((ext_vector_type(4)));

// ---------------- helpers ----------------
__device__ __forceinline__ float wredMax(float v){
  #pragma unroll
  for (int o = 32; o; o >>= 1) v = fmaxf(v, __shfl_xor(v, o, 64));
  return v;
}
__device__ __forceinline__ float wredSum(float v){
  #pragma unroll
  for (int o = 32; o; o >>= 1) v += __shfl_xor(v, o, 64);
  return v;
}
// order-preserving float<->int for atomicMax (no NaN/Inf in inputs)
__device__ __forceinline__ int f2ord(float f){ int i = __float_as_int(f); return i >= 0 ? i : (i ^ 0x7fffffff); }
__device__ __forceinline__ float ord2f(int i){ return __int_as_float(i >= 0 ? i : (i ^ 0x7fffffff)); }

// f32 -> bf16 round-nearest-even (bit trick; inputs are well-behaved, no NaN/Inf)
__device__ __forceinline__ unsigned short f2bf(float x){
  unsigned int u = __float_as_uint(x);
  return (unsigned short)((u + 0x7fffu + ((u >> 16) & 1u)) >> 16);
}
__device__ __forceinline__ float bf2f(unsigned short h){
  return __uint_as_float((unsigned int)h << 16);
}

// ---------------- split conversion: f32 [R][512] -> bf16 [R][1024] = [hi(512) | lo(512)] ----------------
__device__ __forceinline__ void conv_body(const float* __restrict__ src,
                                          unsigned short* __restrict__ dst, int idx)
{
  const float* s = src + (size_t)idx * 8;
  float4 f0 = *(const float4*)s;
  float4 f1 = *(const float4*)(s + 4);
  float fv[8] = {f0.x, f0.y, f0.z, f0.w, f1.x, f1.y, f1.z, f1.w};
  s16x8 vh, vl;
  #pragma unroll
  for (int e = 0; e < 8; ++e) {
    unsigned short h = f2bf(fv[e]);
    vh[e] = (short)h;
    vl[e] = (short)f2bf(fv[e] - bf2f(h));
  }
  int r = idx >> 6, c8 = idx & 63;           // 64 8-elem groups per row (K=512)
  unsigned short* d = dst + (size_t)r * 1024 + c8 * 8;
  *(s16x8*)d = vh;
  *(s16x8*)(d + 512) = vl;
}

struct ConvArgs {
  const float* src[10];
  unsigned short* dst[10];
  int rows[10];
};

__global__ __launch_bounds__(256)
void conv_batch(ConvArgs a)
{
  int z = blockIdx.y;
  int idx = blockIdx.x * 256 + threadIdx.x;
  if (idx >= a.rows[z] * 64) return;
  conv_body(a.src[z], a.dst[z], idx);
}

// ---------------- split-bf16 MFMA NT GEMM (C x C transition) ----------------
// C[m,n] = sum_k A[m,k]*B[n,k] via 3 bf16 products: Ahi*Bhi + Alo*Bhi + Ahi*Blo.
// A,B split as [hi(K)|lo(K)], row stride 2K. 128x128 tile, BK=64, 4 waves (2x2).
// LDS XOR-swizzle: byte ^= (row&7)<<4 on write and read -> conflict-free.
// Flattened 1024-block grid with XCD-bijective swizzle (nwg%8==0).
__global__ __launch_bounds__(256)
void gemm_cc(const unsigned short* __restrict__ Asp, const unsigned short* __restrict__ Bsp,
             float* __restrict__ Co)
{
  constexpr int BM = 128, BN = 128, K = NH, N = NC;
  constexpr int MF = 4, NFR = 4;
  __shared__ char smem[BM * 128 + BN * 128];
  char* smA = smem;
  char* smB = smem + BM * 128;

  const int bid = blockIdx.x;                 // 1024 blocks
  const int swz = (bid & 7) * 128 + (bid >> 3);  // XCD-contiguous chunks
  const int bm = (swz >> 5) * BM, bn = (swz & 31) * BN;

  const int tid  = threadIdx.x;
  const int lane = tid & 63, w = tid >> 6;
  const int wr = w >> 1, wc = w & 1;
  const int lda = 2 * K;
  const int l8 = lane >> 3, s8 = lane & 7;
  const int frow = lane & 15, kgrp = lane >> 4;

  f32x4 acc[MF][NFR] = {};

  #pragma unroll 1
  for (int seg = 0; seg < 3; ++seg) {
    const int aoff = (seg == 1) ? K : 0;
    const int boff = (seg == 2) ? K : 0;
    #pragma unroll 1
    for (int k0 = 0; k0 < K; k0 += 64) {
      #pragma unroll
      for (int c = 0; c < MF; ++c) {
        int q = w * MF + c;
        int row = q * 8 + l8;
        s16x8 v = *(const s16x8*)(Asp + (size_t)(bm + row) * lda + aoff + k0 + s8 * 8);
        unsigned int o = (unsigned int)(row * 128 + (s8 << 4));
        o ^= (unsigned int)((row & 7) << 4);
        *(s16x8*)(smA + o) = v;
      }
      #pragma unroll
      for (int c = 0; c < NFR; ++c) {
        int q = w * NFR + c;
        int row = q * 8 + l8;
        s16x8 v = *(const s16x8*)(Bsp + (size_t)(bn + row) * lda + boff + k0 + s8 * 8);
        unsigned int o = (unsigned int)(row * 128 + (s8 << 4));
        o ^= (unsigned int)((row & 7) << 4);
        *(s16x8*)(smB + o) = v;
      }
      __syncthreads();
      #pragma unroll
      for (int kk = 0; kk < 64; kk += 32) {
        s16x8 af[MF], bfr[NFR];
        #pragma unroll
        for (int im = 0; im < MF; ++im) {
          int ar = wr * (BM / 2) + im * 16 + frow;
          unsigned int o = ((unsigned int)(ar * 128 + (kk + kgrp * 8) * 2)) ^ ((unsigned int)((ar & 7) << 4));
          af[im] = *(const s16x8*)(smA + o);
        }
        #pragma unroll
        for (int jn = 0; jn < NFR; ++jn) {
          int bc = wc * 64 + jn * 16 + frow;
          unsigned int o = ((unsigned int)(bc * 128 + (kk + kgrp * 8) * 2)) ^ ((unsigned int)((bc & 7) << 4));
          bfr[jn] = *(const s16x8*)(smB + o);
        }
        #pragma unroll
        for (int im = 0; im < MF; ++im)
          #pragma unroll
          for (int jn = 0; jn < NFR; ++jn)
            asm volatile("v_mfma_f32_16x16x32_bf16 %0, %1, %2, %0"
                         : "+v"(acc[im][jn]) : "v"(af[im]), "v"(bfr[jn]));
      }
      __syncthreads();
    }
  }
  asm volatile("s_nop 7\n\ts_nop 7" ::: );
  #pragma unroll
  for (int im = 0; im < MF; ++im) {
    int row0 = bm + wr * (BM / 2) + im * 16 + kgrp * 4;
    #pragma unroll
    for (int jn = 0; jn < NFR; ++jn) {
      int col = bn + wc * 64 + jn * 16 + frow;
      #pragma unroll
      for (int j = 0; j < 4; ++j)
        Co[(size_t)(row0 + j) * N + col] = acc[im][jn][j];
    }
  }
}

// ---------------- z-batched H x H res-MLP GEMM (3 branches in one launch) ----------------
// C = relu(A @ B^T + bias (+res)); outputs: f32 (Cf[z]) and/or split bf16 (Cs[z]).
struct G3 {
  const unsigned short* A[3];
  const unsigned short* B[3];
  const float* bias[3];
  const float* res[3];
  float* Cf[3];
  unsigned short* Cs[3];
};

template<bool RES>
__global__ __launch_bounds__(256)
void gemm3(G3 a)
{
  constexpr int BM = 64, BN = 128, K = 512, N = 512;
  constexpr int MF = 2, NFR = 4;
  __shared__ char smem[BM * 128 + BN * 128];
  char* smA = smem;
  char* smB = smem + BM * 128;

  const int z = blockIdx.z;
  const unsigned short* Asp = a.A[z];
  const unsigned short* Bsp = a.B[z];
  const float* bias = a.bias[z];
  float* Cf = a.Cf[z];
  unsigned short* Cs = a.Cs[z];

  const int tid  = threadIdx.x;
  const int lane = tid & 63, w = tid >> 6;
  const int wr = w >> 1, wc = w & 1;
  const int bm = blockIdx.y * BM, bn = blockIdx.x * BN;
  const int lda = 2 * K;
  const int l8 = lane >> 3, s8 = lane & 7;
  const int frow = lane & 15, kgrp = lane >> 4;

  f32x4 acc[MF][NFR] = {};

  #pragma unroll 1
  for (int seg = 0; seg < 3; ++seg) {
    const int aoff = (seg == 1) ? K : 0;
    const int boff = (seg == 2) ? K : 0;
    #pragma unroll 1
    for (int k0 = 0; k0 < K; k0 += 64) {
      #pragma unroll
      for (int c = 0; c < MF; ++c) {
        int q = w * MF + c;
        int row = q * 8 + l8;
        s16x8 v = *(const s16x8*)(Asp + (size_t)(bm + row) * lda + aoff + k0 + s8 * 8);
        unsigned int o = (unsigned int)(row * 128 + (s8 << 4));
        o ^= (unsigned int)((row & 7) << 4);
        *(s16x8*)(smA + o) = v;
      }
      #pragma unroll
      for (int c = 0; c < NFR; ++c) {
        int q = w * NFR + c;
        int row = q * 8 + l8;
        s16x8 v = *(const s16x8*)(Bsp + (size_t)(bn + row) * lda + boff + k0 + s8 * 8);
        unsigned int o = (unsigned int)(row * 128 + (s8 << 4));
        o ^= (unsigned int)((row & 7) << 4);
        *(s16x8*)(smB + o) = v;
      }
      __syncthreads();
      #pragma unroll
      for (int kk = 0; kk < 64; kk += 32) {
        s16x8 af[MF], bfr[NFR];
        #pragma unroll
        for (int im = 0; im < MF; ++im) {
          int ar = wr * (BM / 2) + im * 16 + frow;
          unsigned int o = ((unsigned int)(ar * 128 + (kk + kgrp * 8) * 2)) ^ ((unsigned int)((ar & 7) << 4));
          af[im] = *(const s16x8*)(smA + o);
        }
        #pragma unroll
        for (int jn = 0; jn < NFR; ++jn) {
          int bc = wc * 64 + jn * 16 + frow;
          unsigned int o = ((unsigned int)(bc * 128 + (kk + kgrp * 8) * 2)) ^ ((unsigned int)((bc & 7) << 4));
          bfr[jn] = *(const s16x8*)(smB + o);
        }
        #pragma unroll
        for (int im = 0; im < MF; ++im)
          #pragma unroll
          for (int jn = 0; jn < NFR; ++jn)
            asm volatile("v_mfma_f32_16x16x32_bf16 %0, %1, %2, %0"
                         : "+v"(acc[im][jn]) : "v"(af[im]), "v"(bfr[jn]));
      }
      __syncthreads();
    }
  }
  asm volatile("s_nop 7\n\ts_nop 7" ::: );
  #pragma unroll
  for (int im = 0; im < MF; ++im) {
    int row0 = bm + wr * (BM / 2) + im * 16 + kgrp * 4;
    #pragma unroll
    for (int jn = 0; jn < NFR; ++jn) {
      int col = bn + wc * 64 + jn * 16 + frow;
      #pragma unroll
      for (int j = 0; j < 4; ++j) {
        int r = row0 + j;
        float v = acc[im][jn][j] + bias[col];
        if constexpr (RES) v += a.res[z][(size_t)r * N + col];
        v = fmaxf(v, 0.f);
        if (Cf) Cf[(size_t)r * N + col] = v;
        if (Cs) {
          unsigned short hi = f2bf(v);
          Cs[(size_t)r * 1024 + col] = hi;
          Cs[(size_t)r * 1024 + 512 + col] = f2bf(v - bf2f(hi));
        }
      }
    }
  }
}

// ---------------- start head ----------------
__global__ __launch_bounds__(64)
void dot_head(const float* __restrict__ hS, const float* __restrict__ w3,
              const float* __restrict__ b3, float* __restrict__ sv)
{
  int c = blockIdx.x, lane = threadIdx.x;
  const float* hrow = hS + (size_t)c * NH;
  float acc = 0.f;
  #pragma unroll
  for (int e = 0; e < 8; ++e) acc += hrow[lane + e*64] * w3[lane + e*64];
  acc = wredSum(acc);
  if (lane == 0) sv[c] = acc + b3[0];
}

// ---------------- logsumexp over a length-n vector (single block) ----------------
__global__ __launch_bounds__(1024)
void lse_vec(const float* __restrict__ x, int n, float* __restrict__ out)
{
  int tid = threadIdx.x;
  __shared__ float sm[16], ss[16];
  float m = -INFINITY;
  for (int i = tid; i < n; i += 1024) m = fmaxf(m, x[i]);
  m = wredMax(m);
  if ((tid & 63) == 0) sm[tid >> 6] = m;
  __syncthreads();
  m = sm[0];
  #pragma unroll
  for (int wv = 1; wv < 16; ++wv) m = fmaxf(m, sm[wv]);
  float s = 0.f;
  for (int i = tid; i < n; i += 1024) s += expf(x[i] - m);
  s = wredSum(s);
  if ((tid & 63) == 0) ss[tid >> 6] = s;
  __syncthreads();
  if (tid == 0) {
    float tot = 0.f;
    #pragma unroll
    for (int wv = 0; wv < 16; ++wv) tot += ss[wv];
    out[0] = m + logf(tot);
  }
}

// ---------------- per-row LSE of tl over cols 0..NC-2 (float4 vectorized) ----------------
__global__ __launch_bounds__(256)
void row_lse_trans(const float* __restrict__ tl, float* __restrict__ lse_t)
{
  int c = blockIdx.x;
  const float* row = tl + (size_t)c * NC;
  int tid = threadIdx.x;
  __shared__ float sm[4], ss[4];
  float4 vals[4];
  float m = -INFINITY;
  #pragma unroll
  for (int r = 0; r < 4; ++r) {
    int base = tid * 4 + r * 1024;
    float4 vv = *(const float4*)(row + base);
    if (base + 3 == NC - 1) vv.w = -INFINITY;   // exclude col NC-1
    vals[r] = vv;
    m = fmaxf(m, fmaxf(fmaxf(vv.x, vv.y), fmaxf(vv.z, vv.w)));
  }
  m = wredMax(m);
  if ((tid & 63) == 0) sm[tid >> 6] = m;
  __syncthreads();
  m = fmaxf(fmaxf(sm[0], sm[1]), fmaxf(sm[2], sm[3]));
  float s = 0.f;
  #pragma unroll
  for (int r = 0; r < 4; ++r) {
    float4 vv = vals[r];
    s += expf(vv.x - m) + expf(vv.y - m) + expf(vv.z - m) + expf(vv.w - m);
  }
  s = wredSum(s);
  if ((tid & 63) == 0) ss[tid >> 6] = s;
  __syncthreads();
  if (tid == 0) lse_t[c] = m + logf(ss[0] + ss[1] + ss[2] + ss[3]);
}

// ---------------- emission gathered logits, state-chunked for L2 residency ----------------
// Pass P covers states [P*2048, P*2048+2048): hP chunk = 4 MB = one XCD L2.
// Folds atomicMax(emax) (duplicates carry identical values -> max unaffected).
template<int PASS>
__global__ __launch_bounds__(256)
void el_chunk(const int* __restrict__ w2s, const float* __restrict__ hP,
              const float* __restrict__ w3, const float* __restrict__ b3,
              float* __restrict__ el_g, unsigned int* __restrict__ vmask,
              int* __restrict__ emax)
{
  constexpr int C0 = PASS * (NC / 2), C1 = C0 + (NC / 2);
  int v = blockIdx.x;
  __shared__ float w3v[NH];
  __shared__ int crow[NS];
  int tid = threadIdx.x;
  if (tid < NS) crow[tid] = w2s[(size_t)v * NS + tid];
  for (int e = tid; e < NH; e += 256) w3v[e] = w3[(size_t)v * NH + e];
  __syncthreads();
  if (PASS == 0 && tid < 64) {
    bool valid = false;
    if (tid < NS) {
      valid = true;
      int c = crow[tid];
      for (int s2 = 0; s2 < tid; ++s2) if (crow[s2] == c) { valid = false; break; }
    }
    unsigned long long bal = __ballot(valid);
    if (tid == 0) vmask[v] = (unsigned int)(bal & 0xffffffffull);
  }
  int wave = tid >> 6, lane = tid & 63;
  float b3v = b3[v];
  #pragma unroll
  for (int q = 0; q < 8; ++q) {
    int s = wave * 8 + q;
    int c = crow[s];
    if (c < C0 || c >= C1) continue;          // wave-uniform branch
    const float* hrow = hP + (size_t)c * NH;
    float acc = 0.f;
    #pragma unroll
    for (int e = 0; e < 8; ++e) acc += hrow[lane + e*64] * w3v[lane + e*64];
    acc = wredSum(acc);
    if (lane == 0) {
      float val = acc + b3v;
      el_g[(size_t)v * NS + s] = val;
      atomicMax(&emax[c], f2ord(val));
    }
  }
}

// ---------------- emission row-LSE via atomics (deterministic) ----------------
__global__ __launch_bounds__(256)
void init_e(int* __restrict__ emax, unsigned long long* __restrict__ esum)
{
  int i = blockIdx.x * 256 + threadIdx.x;
  if (i < NC) { emax[i] = 0x80000000; esum[i] = 0ull; }
}
__global__ __launch_bounds__(256)
void emit_sum_k(const int* __restrict__ w2s, const float* __restrict__ el_g,
                const unsigned int* __restrict__ vmask, const int* __restrict__ emax,
                unsigned long long* __restrict__ esum)
{
  int idx = blockIdx.x * 256 + threadIdx.x;
  int v = idx >> 5, s = idx & 31;
  if (!((vmask[v] >> s) & 1u)) return;
  int c = w2s[idx];
  float p = expf(el_g[idx] - ord2f(emax[c]));             // in (0,1]
  atomicAdd(&esum[c], (unsigned long long)(p * 0x1p40f)); // fixed-point, deterministic
}
__global__ __launch_bounds__(256)
void emit_fin_k(const int* __restrict__ emax, const unsigned long long* __restrict__ esum,
                float* __restrict__ lse_e)
{
  int c = blockIdx.x * 256 + threadIdx.x;
  if (c < NC) lse_e[c] = ord2f(emax[c]) + logf((float)esum[c] * 0x1p-40f);
}

// ---------------- build_D: folded obs terms + cs_all + beta0 + Dlast ----------------
__global__ __launch_bounds__(256)
void build_D(const int* __restrict__ text, const int* __restrict__ w2s,
             const float* __restrict__ el_g, const float* __restrict__ lse_e,
             const float* __restrict__ lse_t, const float* __restrict__ sv,
             const float* __restrict__ lse_s,
             float* __restrict__ Dall, float* __restrict__ Dlast,
             float* __restrict__ beta0, unsigned short* __restrict__ cs_all)
{
  int idx = blockIdx.x * 256 + threadIdx.x;   // < NB*NT*NS
  int s = idx & 31;
  int bt = idx >> 5;
  int t = bt & (NT - 1);
  int b = bt >> 8;
  int v = text[bt];
  int c = w2s[(size_t)v * NS + s];
  cs_all[idx] = (unsigned short)c;
  float D = el_g[(size_t)v * NS + s] - lse_e[c] - lse_t[c];
  Dall[idx] = D;
  if (t == NT - 1) Dlast[b * NS + s] = D + lse_t[c];
  if (t == 0)      beta0[b * NS + s] = sv[c] - lse_s[0] + D;
}

// ---------------- full-device gather of scan potentials ----------------
// pot[b][t][j*32+i] = tl[cs[b][t][i] * NC + cs[b][t+1][j]]
__global__ __launch_bounds__(1024)
void gather_pot(const unsigned short* __restrict__ cs_all, const float* __restrict__ tl,
                float* __restrict__ pot)
{
  int t = blockIdx.x;          // 0..NT-2
  int b = blockIdx.y;
  int tid = threadIdx.x;
  __shared__ unsigned short c1s[NS], c2s[NS];
  if (tid < NS) c1s[tid] = cs_all[((size_t)b * NT + t) * NS + tid];
  else if (tid < 2 * NS) c2s[tid - NS] = cs_all[((size_t)b * NT + t + 1) * NS + (tid - NS)];
  __syncthreads();
  int gi = tid >> 5, gj = tid & 31;
  float v = tl[(size_t)c1s[gi] * NC + c2s[gj]];
  pot[((size_t)b * (NT - 1) + t) * 1024 + gj * 32 + gi] = v;
}

// ---------------- single-wave scan step: LSE over i of (pot[j][i] + beta[i]) ----------------
__device__ __forceinline__ float lse_step(float4 p0, float4 p1, float4 p2, float4 p3,
                                          float beta, int h16)
{
  float pv[16] = {p0.x,p0.y,p0.z,p0.w, p1.x,p1.y,p1.z,p1.w,
                  p2.x,p2.y,p2.z,p2.w, p3.x,p3.y,p3.z,p3.w};
  float xs[16];
  #pragma unroll
  for (int q = 0; q < 16; ++q)
    xs[q] = pv[q] + __shfl(beta, h16 + q, 64);   // beta[i] lives in lane i of each half
  float a[8];
  #pragma unroll
  for (int q = 0; q < 8; ++q) a[q] = fmaxf(xs[q], xs[q + 8]);
  float c4[4];
  #pragma unroll
  for (int q = 0; q < 4; ++q) c4[q] = fmaxf(a[q], a[q + 4]);
  float m = fmaxf(fmaxf(c4[0], c4[1]), fmaxf(c4[2], c4[3]));
  m = fmaxf(m, __shfl_xor(m, 32, 64));           // combine halves
  float e[8];
  #pragma unroll
  for (int q = 0; q < 8; ++q) e[q] = __expf(xs[q] - m) + __expf(xs[q + 8] - m);
  float s4[4];
  #pragma unroll
  for (int q = 0; q < 4; ++q) s4[q] = e[q] + e[q + 4];
  float st = (s4[0] + s4[1]) + (s4[2] + s4[3]);
  st += __shfl_xor(st, 32, 64);
  return m + __logf(st);
}

// ---------------- forward-algorithm scan: ONE WAVE per batch element, no barriers ----------------
__global__ __launch_bounds__(64)
void scan_kernel(const float* __restrict__ pot, const float* __restrict__ Dall,
                 const float* __restrict__ Dlast, const float* __restrict__ beta0,
                 float* __restrict__ out_b)
{
  const int b = blockIdx.x;
  const int lane = threadIdx.x;
  const int j = lane & 31;
  const int h16 = (lane >> 5) * 16;
  const float* potb = pot + (size_t)b * (NT - 1) * 1024 + j * 32 + h16;
  const float* Db = Dall + (size_t)b * NT * NS + j;

  float beta = beta0[b * NS + j];

  // depth-2 register double-buffer: A = even slices, B = odd slices
  float4 A0 = *(const float4*)(potb + 0);
  float4 A1 = *(const float4*)(potb + 4);
  float4 A2 = *(const float4*)(potb + 8);
  float4 A3 = *(const float4*)(potb + 12);
  const float* pB0 = potb + 1024;
  float4 B0 = *(const float4*)(pB0 + 0);
  float4 B1 = *(const float4*)(pB0 + 4);
  float4 B2 = *(const float4*)(pB0 + 8);
  float4 B3 = *(const float4*)(pB0 + 12);
  float dA = Db[1 * NS];
  float dB = Db[2 * NS];

  #pragma unroll 1
  for (int t = 0; t < NT - 2; t += 2) {        // t = 0,2,...,252
    float r = lse_step(A0, A1, A2, A3, beta, h16);
    beta = r + dA;
    const float* pn = potb + (size_t)(t + 2) * 1024;
    A0 = *(const float4*)(pn + 0);
    A1 = *(const float4*)(pn + 4);
    A2 = *(const float4*)(pn + 8);
    A3 = *(const float4*)(pn + 12);
    dA = Db[(t + 3 < NT ? t + 3 : NT - 1) * NS];
    float r2 = lse_step(B0, B1, B2, B3, beta, h16);
    beta = r2 + dB;
    int tb = (t + 3 < NT - 1) ? t + 3 : NT - 2;
    const float* pn2 = potb + (size_t)tb * 1024;
    B0 = *(const float4*)(pn2 + 0);
    B1 = *(const float4*)(pn2 + 4);
    B2 = *(const float4*)(pn2 + 8);
    B3 = *(const float4*)(pn2 + 12);
    dB = Db[(t + 4 < NT ? t + 4 : NT - 1) * NS];
  }
  float r = lse_step(A0, A1, A2, A3, beta, h16);
  float rfin = r + Dlast[b * NS + j];

  float m = rfin;
  #pragma unroll
  for (int o = 16; o; o >>= 1) m = fmaxf(m, __shfl_xor(m, o, 32));
  float p = expf(rfin - m);
  #pragma unroll
  for (int o = 16; o; o >>= 1) p += __shfl_xor(p, o, 32);
  if (lane == 0) out_b[b] = m + logf(p);
}

__global__ void final_sum(const float* __restrict__ out_b, float* __restrict__ out)
{
  if (threadIdx.x == 0) {
    float s = 0.f;
    for (int b = 0; b < NB; ++b) s += out_b[b];
    out[0] = s;
  }
}

// ---------------- launch ----------------
extern "C" void kernel_launch(void* const* d_in, const int* in_sizes, int n_in,
                              void* d_out, int out_size, void* d_ws, size_t ws_size,
                              hipStream_t stream)
{
  (void)in_sizes; (void)n_in; (void)out_size; (void)ws_size;
  const int*   text      = (const int*)d_in[0];
  const int*   w2s       = (const int*)d_in[1];
  const float* start_emb = (const float*)d_in[2];
  const float* start_w1  = (const float*)d_in[3];
  const float* start_b1  = (const float*)d_in[4];
  const float* start_w2  = (const float*)d_in[5];
  const float* start_b2  = (const float*)d_in[6];
  const float* start_w3  = (const float*)d_in[7];
  const float* start_b3  = (const float*)d_in[8];
  const float* state_emb = (const float*)d_in[9];
  const float* trans_w1  = (const float*)d_in[10];
  const float* trans_b1  = (const float*)d_in[11];
  const float* trans_w2  = (const float*)d_in[12];
  const float* trans_b2  = (const float*)d_in[13];
  const float* nsp       = (const float*)d_in[14];
  const float* pre_emb   = (const float*)d_in[15];
  const float* term_w1   = (const float*)d_in[16];
  const float* term_b1   = (const float*)d_in[17];
  const float* term_w2   = (const float*)d_in[18];
  const float* term_b2   = (const float*)d_in[19];
  const float* term_w3   = (const float*)d_in[20];
  const float* term_b3   = (const float*)d_in[21];

  // ---- workspace arena (~136.45 MB; proven available) ----
  float* tl    = (float*)d_ws;                     // 16,777,216 f (64 MB)
  float* el_g  = tl + 16777216;                    // 1,024,000 f
  float* sv    = el_g + 1024000;                   // 4096
  float* lse_t = sv + 4096;                        // 4096
  float* lse_e = lse_t + 4096;                     // 4096
  float* lse_s = lse_e + 4096;                     // 64
  float* out_b = lse_s + 64;                       // 64
  float* Dlast = out_b + 64;                       // 1024
  float* beta0 = Dlast + 1024;                     // 1024
  unsigned int* vmask = (unsigned int*)(beta0 + 1024);            // 32,768 u32
  int* emax = (int*)(vmask + 32768);                              // 4096 i32
  unsigned long long* esum = (unsigned long long*)(emax + 4096);  // 4096 u64
  unsigned short* sE_s  = (unsigned short*)(esum + 4096);  // 4096x1024 u16 each:
  unsigned short* tE_s  = sE_s  + 4194304;
  unsigned short* pE_s  = tE_s  + 4194304;
  unsigned short* nsp_s = pE_s  + 4194304;
  unsigned short* w1S_s = nsp_s + 4194304;         // 512x1024 u16 each:
  unsigned short* w2S_s = w1S_s + 524288;
  unsigned short* w1T_s = w2S_s + 524288;
  unsigned short* w2T_s = w1T_s + 524288;
  unsigned short* w1P_s = w2T_s + 524288;
  unsigned short* w2P_s = w1P_s + 524288;
  unsigned short* h1s0  = w2P_s + 524288;          // 4096x1024 u16 each (split h1):
  unsigned short* h1s1  = h1s0 + 4194304;
  unsigned short* h1s2  = h1s1 + 4194304;
  // aliases (lifetime-disjoint):
  float* h2f0 = (float*)sE_s;        // start h2 f32  (sE dead after GEMM1)
  unsigned short* h2s1 = tE_s;       // trans h2 split (tE dead after GEMM1)
  float* h2f2 = (float*)pE_s;        // term h2 f32   (pE dead after GEMM1)
  float* pot  = (float*)sE_s;        // 8,355,840 f over sE..nsp (dead after heads/CxC/el)
  float* Dall = (float*)h1s0;        // 262,144 f (h1s dead after GEMM2)
  unsigned short* cs_all = (unsigned short*)((char*)h1s0 + 1048576);  // 262,144 u16

  // ---- upfront split conversions (10 matrices, one launch) ----
  ConvArgs ca;
  ca.src[0]=start_emb; ca.dst[0]=sE_s;  ca.rows[0]=NC;
  ca.src[1]=state_emb; ca.dst[1]=tE_s;  ca.rows[1]=NC;
  ca.src[2]=pre_emb;   ca.dst[2]=pE_s;  ca.rows[2]=NC;
  ca.src[3]=nsp;       ca.dst[3]=nsp_s; ca.rows[3]=NC;
  ca.src[4]=start_w1;  ca.dst[4]=w1S_s; ca.rows[4]=NH;
  ca.src[5]=start_w2;  ca.dst[5]=w2S_s; ca.rows[5]=NH;
  ca.src[6]=trans_w1;  ca.dst[6]=w1T_s; ca.rows[6]=NH;
  ca.src[7]=trans_w2;  ca.dst[7]=w2T_s; ca.rows[7]=NH;
  ca.src[8]=term_w1;   ca.dst[8]=w1P_s; ca.rows[8]=NH;
  ca.src[9]=term_w2;   ca.dst[9]=w2P_s; ca.rows[9]=NH;
  conv_batch<<<dim3(1024, 10), 256, 0, stream>>>(ca);

  // ---- z-batched res-MLP: GEMM1 (split out), GEMM2 (f32/split per branch) ----
  G3 g1;
  g1.A[0]=sE_s;  g1.A[1]=tE_s;  g1.A[2]=pE_s;
  g1.B[0]=w1S_s; g1.B[1]=w1T_s; g1.B[2]=w1P_s;
  g1.bias[0]=start_b1; g1.bias[1]=trans_b1; g1.bias[2]=term_b1;
  g1.res[0]=nullptr; g1.res[1]=nullptr; g1.res[2]=nullptr;
  g1.Cf[0]=nullptr; g1.Cf[1]=nullptr; g1.Cf[2]=nullptr;
  g1.Cs[0]=h1s0; g1.Cs[1]=h1s1; g1.Cs[2]=h1s2;
  gemm3<false><<<dim3(4, 64, 3), 256, 0, stream>>>(g1);

  G3 g2;
  g2.A[0]=h1s0;  g2.A[1]=h1s1;  g2.A[2]=h1s2;
  g2.B[0]=w2S_s; g2.B[1]=w2T_s; g2.B[2]=w2P_s;
  g2.bias[0]=start_b2; g2.bias[1]=trans_b2; g2.bias[2]=term_b2;
  g2.res[0]=start_emb; g2.res[1]=state_emb; g2.res[2]=pre_emb;
  g2.Cf[0]=h2f0; g2.Cf[1]=nullptr; g2.Cf[2]=h2f2;
  g2.Cs[0]=nullptr; g2.Cs[1]=h2s1; g2.Cs[2]=nullptr;
  gemm3<true><<<dim3(4, 64, 3), 256, 0, stream>>>(g2);

  // start head
  dot_head<<<NC, 64, 0, stream>>>(h2f0, start_w3, start_b3, sv);
  lse_vec<<<1, 1024, 0, stream>>>(sv, NC, lse_s);

  // emission logits, state-chunked (hP = h2f2 still L2-warm), max folded in
  init_e<<<16, 256, 0, stream>>>(emax, esum);
  el_chunk<0><<<NV, 256, 0, stream>>>(w2s, h2f2, term_w3, term_b3, el_g, vmask, emax);
  el_chunk<1><<<NV, 256, 0, stream>>>(w2s, h2f2, term_w3, term_b3, el_g, vmask, emax);
  emit_sum_k<<<NV * NS / 256, 256, 0, stream>>>(w2s, el_g, vmask, emax, esum);
  emit_fin_k<<<NC / 256, 256, 0, stream>>>(emax, esum, lse_e);

  // transition C x C + row LSE
  gemm_cc<<<1024, 256, 0, stream>>>(h2s1, nsp_s, tl);
  row_lse_trans<<<NC, 256, 0, stream>>>(tl, lse_t);

  // folded obs terms + full-device gather of scan potentials
  build_D<<<NB * NT * NS / 256, 256, 0, stream>>>(text, w2s, el_g, lse_e, lse_t, sv, lse_s,
                                                  Dall, Dlast, beta0, cs_all);
  gather_pot<<<dim3(NT - 1, NB), 1024, 0, stream>>>(cs_all, tl, pot);

  // scan + final
  scan_kernel<<<NB, 64, 0, stream>>>(pot, Dall, Dlast, beta0, out_b);
  final_sum<<<1, 64, 0, stream>>>(out_b, (float*)d_out);
}